// Round 8
// baseline (1351.140 us; speedup 1.0000x reference)
//
#include <hip/hip_runtime.h>
#include <cmath>

#define NNODES 50000
#define NEDGES 600000
#define NBATCH 50
#define SCAN_BLOCK 256
#define NCHUNK ((NNODES + SCAN_BLOCK - 1) / SCAN_BLOCK)   // 196

// ============================ CSR build ============================
__global__ void hist_kernel(const int* __restrict__ dst, int* __restrict__ deg){
  int e = blockIdx.x*blockDim.x + threadIdx.x;
  if(e < NEDGES) atomicAdd(&deg[dst[e]], 1);
}

__global__ void deg_partial(const int* __restrict__ deg, int* __restrict__ part){
  __shared__ int red[SCAN_BLOCK];
  int t = threadIdx.x, id = blockIdx.x*SCAN_BLOCK + t;
  red[t] = (id < NNODES) ? deg[id] : 0;
  __syncthreads();
  for(int o = SCAN_BLOCK/2; o > 0; o >>= 1){
    if(t < o) red[t] += red[t+o];
    __syncthreads();
  }
  if(t == 0) part[blockIdx.x] = red[0];
}

__global__ void part_scan(int* __restrict__ part){
  __shared__ int ps[256];
  int t = threadIdx.x;
  int v = (t < NCHUNK) ? part[t] : 0;
  ps[t] = v; __syncthreads();
  for(int o=1;o<256;o<<=1){
    int u = (t>=o) ? ps[t-o] : 0;
    __syncthreads();
    ps[t] += u;
    __syncthreads();
  }
  if(t < NCHUNK) part[t] = ps[t] - v;   // exclusive
}

__global__ void scan_final(const int* __restrict__ deg, const int* __restrict__ part,
                           int* __restrict__ off, int* __restrict__ cur){
  __shared__ int ps[SCAN_BLOCK];
  int t = threadIdx.x, id = blockIdx.x*SCAN_BLOCK + t;
  int v = (id < NNODES) ? deg[id] : 0;
  ps[t] = v; __syncthreads();
  for(int o=1;o<SCAN_BLOCK;o<<=1){
    int u = (t>=o) ? ps[t-o] : 0;
    __syncthreads();
    ps[t] += u;
    __syncthreads();
  }
  int excl = ps[t] - v + part[blockIdx.x];
  if(id < NNODES){ off[id] = excl; cur[id] = excl; }
  if(id == 0) off[NNODES] = NEDGES;
}

__global__ void scatter_kernel(const int* __restrict__ src, const int* __restrict__ dst,
                               const float* __restrict__ ea, int* __restrict__ cur,
                               int* __restrict__ csr_src, float2* __restrict__ csr_ea){
  int e = blockIdx.x*blockDim.x + threadIdx.x;
  if(e >= NEDGES) return;
  int d = dst[e];
  int p = atomicAdd(&cur[d], 1);
  csr_src[p] = src[e];
  csr_ea[p] = make_float2(ea[2*e], ea[2*e+1]);
}

// ============================ conv0 linear (K=4), both outputs ============================
__global__ void gemm_k4_dual(const float* __restrict__ x,
                             const float* __restrict__ Wa, const float* __restrict__ ba,
                             const float* __restrict__ Wb, const float* __restrict__ bb,
                             float* __restrict__ outa, float* __restrict__ outb){
  int idx = blockIdx.x*blockDim.x + threadIdx.x;
  if(idx >= NNODES*128) return;
  int r = idx >> 7, c = idx & 127;
  float4 xv = *(const float4*)&x[r*4];
  float acca = ba[c] + xv.x*Wa[c] + xv.y*Wa[128+c] + xv.z*Wa[256+c] + xv.w*Wa[384+c];
  float accb = bb[c] + xv.x*Wb[c] + xv.y*Wb[128+c] + xv.z*Wb[256+c] + xv.w*Wb[384+c];
  outa[idx] = acca;
  outb[idx] = accb;
}

// ============================ dual GEMM: xl = x@Wa+ba, xr = x@Wb+bb ============================
// Only the x-tile lives in LDS (full K, transposed xs[k][row], pad 65 ->
// conflict-free stores, broadcast b128 reads). W comes straight from global:
// 64KB x 2, shared by all blocks on the CU -> L1/L2-hot coalesced reads.
// LDS 41.5KB -> 33.3KB: 3 -> 4 blocks/CU; 8 barriers -> 1 pair.
__launch_bounds__(256)
__global__ void gemm_dual(const float* __restrict__ x,
                          const float* __restrict__ Wa, const float* __restrict__ ba,
                          const float* __restrict__ Wb, const float* __restrict__ bb,
                          float* __restrict__ outa, float* __restrict__ outb, int M){
  __shared__ float xs[128][65];          // [k][row]
  int tid = threadIdx.x;
  int tc = tid & 31, tr = tid >> 5;
  int row0 = blockIdx.x * 64;
  // stage x-tile: 64 rows x 128 k, 32 elems/thread, coalesced along k
  #pragma unroll
  for(int i=0;i<32;i++){
    int l = tid + i*256;                 // 0..8191
    int r = l >> 7, k = l & 127;
    int row = row0 + r;
    xs[k][r] = (row < M) ? x[row*128 + k] : 0.f;
  }
  __syncthreads();
  float acca[8][4], accb[8][4];
  #pragma unroll
  for(int i=0;i<8;i++){
    #pragma unroll
    for(int j=0;j<4;j++){ acca[i][j]=0.f; accb[i][j]=0.f; }
  }
  #pragma unroll 8
  for(int k=0;k<128;k++){
    float4 wa = *(const float4*)&Wa[k*128 + tc*4];
    float4 wb = *(const float4*)&Wb[k*128 + tc*4];
    float4 xv0 = *(float4*)&xs[k][tr*8];
    float4 xv1 = *(float4*)&xs[k][tr*8+4];
    float xv[8] = {xv0.x,xv0.y,xv0.z,xv0.w, xv1.x,xv1.y,xv1.z,xv1.w};
    #pragma unroll
    for(int i=0;i<8;i++){
      acca[i][0] += xv[i]*wa.x; acca[i][1] += xv[i]*wa.y;
      acca[i][2] += xv[i]*wa.z; acca[i][3] += xv[i]*wa.w;
      accb[i][0] += xv[i]*wb.x; accb[i][1] += xv[i]*wb.y;
      accb[i][2] += xv[i]*wb.z; accb[i][3] += xv[i]*wb.w;
    }
  }
  float4 bva = *(const float4*)&ba[tc*4];
  float4 bvb = *(const float4*)&bb[tc*4];
  #pragma unroll
  for(int i=0;i<8;i++){
    int row = row0 + tr*8 + i;
    if(row < M){
      float4 oa = make_float4(acca[i][0]+bva.x, acca[i][1]+bva.y, acca[i][2]+bva.z, acca[i][3]+bva.w);
      float4 ob = make_float4(accb[i][0]+bvb.x, accb[i][1]+bvb.y, accb[i][2]+bvb.z, accb[i][3]+bvb.w);
      *(float4*)&outa[row*128 + tc*4] = oa;
      *(float4*)&outb[row*128 + tc*4] = ob;
    }
  }
}

// ============================ fused GATv2 edge phase ============================
// One wave per destination node; lane l owns channels 2l,2l+1; 16-lane groups = heads.
// ILP=4 edges/iter; node/csr indices forced scalar via readfirstlane.
__launch_bounds__(256)
__global__ void edge_kernel(const float* __restrict__ xl, const float* __restrict__ xr,
                            const int* __restrict__ off, const int* __restrict__ csr_src,
                            const float2* __restrict__ csr_ea,
                            const float* __restrict__ We, const float* __restrict__ att,
                            const float* __restrict__ bias, const float* __restrict__ res,
                            float* __restrict__ out){
  int wid  = (blockIdx.x*blockDim.x + threadIdx.x) >> 6;
  int lane = threadIdx.x & 63;
  if(wid >= NNODES) return;
  int node = __builtin_amdgcn_readfirstlane(wid);   // provably wave-uniform
  int c0 = lane*2;
  float2 xr2 = *(const float2*)&xr[node*128 + c0];
  float2 xls = *(const float2*)&xl[node*128 + c0];
  float2 av  = *(const float2*)&att[c0];
  float2 w0  = *(const float2*)&We[c0];
  float2 w1  = *(const float2*)&We[128 + c0];

  // self-loop (src=node, ea=0)
  float zx = xls.x + xr2.x; zx = zx > 0.f ? zx : 0.2f*zx;
  float zy = xls.y + xr2.y; zy = zy > 0.f ? zy : 0.2f*zy;
  float m = zx*av.x + zy*av.y;
  #pragma unroll
  for(int o=1;o<16;o<<=1) m += __shfl_xor(m, o, 64);
  float den = 1.f;
  float accx = xls.x, accy = xls.y;

  int e0 = off[node], e1 = off[node+1];
  for(int e=e0; e<e1; e+=4){
    int cnt = e1 - e;                       // scalar
    int   s[4];
    float2 ea[4];
    #pragma unroll
    for(int j=0;j<4;j++){
      if(j < cnt){
        s[j]  = __builtin_amdgcn_readfirstlane(csr_src[e+j]);
        ea[j] = csr_ea[e+j];
      } else {
        s[j] = node; ea[j] = make_float2(0.f,0.f);
      }
    }
    float2 xv[4];
    #pragma unroll
    for(int j=0;j<4;j++) xv[j] = *(const float2*)&xl[(size_t)s[j]*128 + c0];
    float p[4];
    #pragma unroll
    for(int j=0;j<4;j++){
      float z0 = xv[j].x + xr2.x + ea[j].x*w0.x + ea[j].y*w1.x; z0 = z0 > 0.f ? z0 : 0.2f*z0;
      float z1 = xv[j].y + xr2.y + ea[j].x*w0.y + ea[j].y*w1.y; z1 = z1 > 0.f ? z1 : 0.2f*z1;
      p[j] = z0*av.x + z1*av.y;
    }
    #pragma unroll
    for(int o=1;o<16;o<<=1){
      #pragma unroll
      for(int j=0;j<4;j++) p[j] += __shfl_xor(p[j], o, 64);
    }
    #pragma unroll
    for(int j=0;j<4;j++) if(j >= cnt) p[j] = -1e30f;
    float nm = m;
    #pragma unroll
    for(int j=0;j<4;j++) nm = fmaxf(nm, p[j]);
    float sc = __expf(m - nm);
    float pe[4];
    #pragma unroll
    for(int j=0;j<4;j++) pe[j] = __expf(p[j] - nm);
    den  = den*sc  + pe[0]+pe[1]+pe[2]+pe[3];
    accx = accx*sc + pe[0]*xv[0].x + pe[1]*xv[1].x + pe[2]*xv[2].x + pe[3]*xv[3].x;
    accy = accy*sc + pe[0]*xv[0].y + pe[1]*xv[1].y + pe[2]*xv[2].y + pe[3]*xv[3].y;
    m = nm;
  }
  float inv = 1.f/(den + 1e-16f);
  float ox = accx*inv + bias[c0];
  float oy = accy*inv + bias[c0+1];
  ox = ox > 0.f ? ox : 0.f;
  oy = oy > 0.f ? oy : 0.f;
  if(res){ ox += res[node*128 + c0]; oy += res[node*128 + c0 + 1]; }
  *(float2*)&out[node*128 + c0] = make_float2(ox, oy);
}

// ============================ pooling ============================
#define POOL_CHUNK 128
__launch_bounds__(128)
__global__ void pool_kernel(const float* __restrict__ x, const int* __restrict__ batch,
                            float* __restrict__ sums, float* __restrict__ maxv,
                            float* __restrict__ cnt){
  int c = threadIdx.x;
  int n0 = blockIdx.x * POOL_CHUNK;
  if(n0 >= NNODES) return;
  int n1 = n0 + POOL_CHUNK; if(n1 > NNODES) n1 = NNODES;
  int curb = batch[n0];
  float s = 0.f, mx = 0.f;
  float segc = 0.f;
  for(int nd = n0; nd < n1; nd++){
    int b = batch[nd];
    if(b != curb){
      atomicAdd(&sums[curb*128 + c], s);
      atomicMax((int*)&maxv[curb*128 + c], __float_as_int(mx));
      if(c == 0) atomicAdd(&cnt[curb], segc);
      curb = b; s = 0.f; mx = 0.f; segc = 0.f;
    }
    float v = x[nd*128 + c];
    s += v; mx = fmaxf(mx, v); segc += 1.f;
  }
  atomicAdd(&sums[curb*128 + c], s);
  atomicMax((int*)&maxv[curb*128 + c], __float_as_int(mx));
  if(c == 0) atomicAdd(&cnt[curb], segc);
}

// ============================ fused dense trunk + heads ============================
__launch_bounds__(128)
__global__ void fused_dense(const float* __restrict__ sums, const float* __restrict__ maxv,
                            const float* __restrict__ cnt,
                            const float* __restrict__ D1_W, const float* __restrict__ D1_b,
                            const float* __restrict__ D23_W, const float* __restrict__ D23_b,
                            const float* __restrict__ H1_W, const float* __restrict__ H1_b,
                            const float* __restrict__ H2_W, const float* __restrict__ H2_b,
                            const float* __restrict__ H3_W, const float* __restrict__ H3_b,
                            float* __restrict__ out){
  __shared__ float X[256];
  __shared__ float y[128];
  __shared__ float z[128];
  int b = blockIdx.x, t = threadIdx.x;
  float ct = cnt[b]; ct = ct > 1.f ? ct : 1.f;
  X[t]       = sums[b*128 + t] / ct;
  X[128 + t] = maxv[b*128 + t];
  __syncthreads();
  float acc = D1_b[t];
  #pragma unroll 16
  for(int k=0;k<256;k++) acc += X[k]*D1_W[k*128+t];
  y[t] = fmaxf(acc, 0.f);
  __syncthreads();
  acc = D23_b[t];
  #pragma unroll 16
  for(int k=0;k<128;k++) acc += y[k]*D23_W[k*128+t];
  z[t] = fmaxf(acc, 0.f);
  __syncthreads();
  acc = D23_b[128+t];
  #pragma unroll 16
  for(int k=0;k<128;k++) acc += z[k]*D23_W[16384 + k*128+t];
  y[t] = fmaxf(acc, 0.f);
  __syncthreads();
  for(int h=0;h<3;h++){
    acc = H1_b[h*128+t];
    #pragma unroll 16
    for(int k=0;k<128;k++) acc += y[k]*H1_W[h*16384 + k*128+t];
    z[t] = fmaxf(acc, 0.f);
    __syncthreads();
    float v = 0.f;
    if(t < 64){
      float a2 = H2_b[h*64+t];
      #pragma unroll 16
      for(int k=0;k<128;k++) a2 += z[k]*H2_W[h*8192 + k*64+t];
      a2 = fmaxf(a2, 0.f);
      v = a2 * H3_W[h*64 + t];
    }
    #pragma unroll
    for(int o=1;o<64;o<<=1) v += __shfl_xor(v, o, 64);
    if(t == 0){
      float r = v + H3_b[h];
      if(h == 0) r = tanhf(r);
      out[b*3 + h] = r;
    }
    __syncthreads();
  }
}

// ============================ launch ============================
extern "C" void kernel_launch(void* const* d_in, const int* in_sizes, int n_in,
                              void* d_out, int out_size, void* d_ws, size_t ws_size,
                              hipStream_t stream) {
  const float* nodes  = (const float*)d_in[0];
  const int*   eidx   = (const int*)  d_in[1];
  const float* eattr  = (const float*)d_in[2];
  const int*   batch  = (const int*)  d_in[3];
  const float* W0l    = (const float*)d_in[4];
  const float* b0l    = (const float*)d_in[5];
  const float* W0r    = (const float*)d_in[6];
  const float* b0r    = (const float*)d_in[7];
  const float* W0e    = (const float*)d_in[8];
  const float* att0   = (const float*)d_in[9];
  const float* bias0  = (const float*)d_in[10];
  const float* Wl     = (const float*)d_in[11];
  const float* bl     = (const float*)d_in[12];
  const float* Wr     = (const float*)d_in[13];
  const float* br     = (const float*)d_in[14];
  const float* We     = (const float*)d_in[15];
  const float* atts   = (const float*)d_in[16];
  const float* biases = (const float*)d_in[17];
  const float* D1_W   = (const float*)d_in[18];
  const float* D1_b   = (const float*)d_in[19];
  const float* D23_W  = (const float*)d_in[20];
  const float* D23_b  = (const float*)d_in[21];
  const float* H1_W   = (const float*)d_in[22];
  const float* H1_b   = (const float*)d_in[23];
  const float* H2_W   = (const float*)d_in[24];
  const float* H2_b   = (const float*)d_in[25];
  const float* H3_W   = (const float*)d_in[26];
  const float* H3_b   = (const float*)d_in[27];

  // ---- workspace layout ----
  char* ws = (char*)d_ws;
  size_t o = 0;
  auto alloc = [&](size_t bytes)->char*{ char* p = ws + o; o = (o + bytes + 255) & ~(size_t)255; return p; };
  int*    deg     = (int*)   alloc(NNODES*4);
  int*    offs    = (int*)   alloc((NNODES+1)*4);
  int*    cur     = (int*)   alloc(NNODES*4);
  int*    part    = (int*)   alloc(NCHUNK*4);
  int*    csr_src = (int*)   alloc(NEDGES*4);
  float2* csr_ea  = (float2*)alloc(NEDGES*8);
  float*  xl      = (float*) alloc((size_t)NNODES*128*4);
  float*  xr      = (float*) alloc((size_t)NNODES*128*4);
  float*  bufA    = (float*) alloc((size_t)NNODES*128*4);
  float*  bufB    = (float*) alloc((size_t)NNODES*128*4);
  float*  pool    = (float*) alloc((NBATCH*128*2 + NBATCH)*4);
  float*  sums    = pool;
  float*  maxv    = pool + NBATCH*128;
  float*  cnt     = pool + NBATCH*256;
  (void)ws_size; (void)in_sizes; (void)n_in; (void)out_size;

  const int* src = eidx;
  const int* dst = eidx + NEDGES;

  // ---- CSR build ----
  hipMemsetAsync(deg, 0, NNODES*4, stream);
  hipMemsetAsync(pool, 0, (NBATCH*128*2 + NBATCH)*4, stream);
  hist_kernel<<<(NEDGES+255)/256, 256, 0, stream>>>(dst, deg);
  deg_partial<<<NCHUNK, SCAN_BLOCK, 0, stream>>>(deg, part);
  part_scan<<<1, 256, 0, stream>>>(part);
  scan_final<<<NCHUNK, SCAN_BLOCK, 0, stream>>>(deg, part, offs, cur);
  scatter_kernel<<<(NEDGES+255)/256, 256, 0, stream>>>(src, dst, eattr, cur, csr_src, csr_ea);

  // ---- conv0 ----
  gemm_k4_dual<<<(NNODES*128+255)/256, 256, 0, stream>>>(nodes, W0l, b0l, W0r, b0r, xl, xr);
  edge_kernel<<<(NNODES+3)/4, 256, 0, stream>>>(xl, xr, offs, csr_src, csr_ea,
                                                W0e, att0, bias0, nullptr, bufA);

  // ---- 4 skip blocks x 2 convs ----
  const int gemm_grid = (NNODES + 63) / 64;
  for(int blk=0; blk<4; blk++){
    int j = 2*blk;
    gemm_dual<<<gemm_grid, 256, 0, stream>>>(bufA, Wl + (size_t)j*16384, bl + j*128,
                                             Wr + (size_t)j*16384, br + j*128, xl, xr, NNODES);
    edge_kernel<<<(NNODES+3)/4, 256, 0, stream>>>(xl, xr, offs, csr_src, csr_ea,
                                                  We + j*256, atts + j*128, biases + j*128,
                                                  nullptr, bufB);
    j = 2*blk + 1;
    gemm_dual<<<gemm_grid, 256, 0, stream>>>(bufB, Wl + (size_t)j*16384, bl + j*128,
                                             Wr + (size_t)j*16384, br + j*128, xl, xr, NNODES);
    edge_kernel<<<(NNODES+3)/4, 256, 0, stream>>>(xl, xr, offs, csr_src, csr_ea,
                                                  We + j*256, atts + j*128, biases + j*128,
                                                  bufA /*residual*/, bufA);
  }

  // ---- pooling + fused dense trunk/heads ----
  pool_kernel<<<(NNODES + POOL_CHUNK - 1)/POOL_CHUNK, 128, 0, stream>>>(bufA, batch, sums, maxv, cnt);
  fused_dense<<<NBATCH, 128, 0, stream>>>(sums, maxv, cnt,
                                          D1_W, D1_b, D23_W, D23_b,
                                          H1_W, H1_b, H2_W, H2_b, H3_W, H3_b,
                                          (float*)d_out);
}

// Round 9
// 1297.707 us; speedup vs baseline: 1.0412x; 1.0412x over previous
//
#include <hip/hip_runtime.h>
#include <cmath>

#define NNODES 50000
#define NEDGES 600000
#define NBATCH 50
#define SCAN_BLOCK 256
#define NCHUNK ((NNODES + SCAN_BLOCK - 1) / SCAN_BLOCK)   // 196

// ============================ CSR build ============================
__global__ void hist_kernel(const int* __restrict__ dst, int* __restrict__ deg){
  int e = blockIdx.x*blockDim.x + threadIdx.x;
  if(e < NEDGES) atomicAdd(&deg[dst[e]], 1);
}

__global__ void deg_partial(const int* __restrict__ deg, int* __restrict__ part){
  __shared__ int red[SCAN_BLOCK];
  int t = threadIdx.x, id = blockIdx.x*SCAN_BLOCK + t;
  red[t] = (id < NNODES) ? deg[id] : 0;
  __syncthreads();
  for(int o = SCAN_BLOCK/2; o > 0; o >>= 1){
    if(t < o) red[t] += red[t+o];
    __syncthreads();
  }
  if(t == 0) part[blockIdx.x] = red[0];
}

__global__ void part_scan(int* __restrict__ part){
  __shared__ int ps[256];
  int t = threadIdx.x;
  int v = (t < NCHUNK) ? part[t] : 0;
  ps[t] = v; __syncthreads();
  for(int o=1;o<256;o<<=1){
    int u = (t>=o) ? ps[t-o] : 0;
    __syncthreads();
    ps[t] += u;
    __syncthreads();
  }
  if(t < NCHUNK) part[t] = ps[t] - v;   // exclusive
}

__global__ void scan_final(const int* __restrict__ deg, const int* __restrict__ part,
                           int* __restrict__ off, int* __restrict__ cur){
  __shared__ int ps[SCAN_BLOCK];
  int t = threadIdx.x, id = blockIdx.x*SCAN_BLOCK + t;
  int v = (id < NNODES) ? deg[id] : 0;
  ps[t] = v; __syncthreads();
  for(int o=1;o<SCAN_BLOCK;o<<=1){
    int u = (t>=o) ? ps[t-o] : 0;
    __syncthreads();
    ps[t] += u;
    __syncthreads();
  }
  int excl = ps[t] - v + part[blockIdx.x];
  if(id < NNODES){ off[id] = excl; cur[id] = excl; }
  if(id == 0) off[NNODES] = NEDGES;
}

__global__ void scatter_kernel(const int* __restrict__ src, const int* __restrict__ dst,
                               const float* __restrict__ ea, int* __restrict__ cur,
                               int* __restrict__ csr_src, float2* __restrict__ csr_ea){
  int e = blockIdx.x*blockDim.x + threadIdx.x;
  if(e >= NEDGES) return;
  int d = dst[e];
  int p = atomicAdd(&cur[d], 1);
  csr_src[p] = src[e];
  csr_ea[p] = make_float2(ea[2*e], ea[2*e+1]);
}

// ============================ conv0 linear (K=4), both outputs ============================
__global__ void gemm_k4_dual(const float* __restrict__ x,
                             const float* __restrict__ Wa, const float* __restrict__ ba,
                             const float* __restrict__ Wb, const float* __restrict__ bb,
                             float* __restrict__ outa, float* __restrict__ outb){
  int idx = blockIdx.x*blockDim.x + threadIdx.x;
  if(idx >= NNODES*128) return;
  int r = idx >> 7, c = idx & 127;
  float4 xv = *(const float4*)&x[r*4];
  float acca = ba[c] + xv.x*Wa[c] + xv.y*Wa[128+c] + xv.z*Wa[256+c] + xv.w*Wa[384+c];
  float accb = bb[c] + xv.x*Wb[c] + xv.y*Wb[128+c] + xv.z*Wb[256+c] + xv.w*Wb[384+c];
  outa[idx] = acca;
  outb[idx] = accb;
}

// ============================ dual GEMM: xl = x@Wa+ba, xr = x@Wb+bb ============================
// 32-row x 128-col tile: grid 1563 blocks (6.1/CU, was 3 -> grid-limited occ),
// acc 64 -> 32 VGPRs so the unroll-4 W-load batch can be register-hoisted
// (R7's VGPR=68 left no room -> serialized loads). x-tile in LDS transposed
// (16.9 KB, never the occupancy binder); W from global (L1/L2-hot, same
// addresses for all blocks).
__launch_bounds__(256)
__global__ void gemm_dual(const float* __restrict__ x,
                          const float* __restrict__ Wa, const float* __restrict__ ba,
                          const float* __restrict__ Wb, const float* __restrict__ bb,
                          float* __restrict__ outa, float* __restrict__ outb, int M){
  __shared__ float xs[128][33];          // [k][row], 32 rows
  int tid = threadIdx.x;
  int tc = tid & 31, tr = tid >> 5;      // tc: 4-col group, tr: 4-row group
  int row0 = blockIdx.x * 32;
  // stage x-tile: 32 rows x 128 k = 4096 elems, 16/thread, coalesced along k
  #pragma unroll
  for(int i=0;i<16;i++){
    int l = tid + i*256;                 // 0..4095
    int r = l >> 7, k = l & 127;
    int row = row0 + r;
    xs[k][r] = (row < M) ? x[row*128 + k] : 0.f;
  }
  __syncthreads();
  float acca[4][4], accb[4][4];
  #pragma unroll
  for(int i=0;i<4;i++){
    #pragma unroll
    for(int j=0;j<4;j++){ acca[i][j]=0.f; accb[i][j]=0.f; }
  }
  #pragma unroll 4
  for(int k=0;k<128;k++){
    float4 wa = *(const float4*)&Wa[k*128 + tc*4];
    float4 wb = *(const float4*)&Wb[k*128 + tc*4];
    float4 xv = *(const float4*)&xs[k][tr*4];
    float xr_[4] = {xv.x, xv.y, xv.z, xv.w};
    #pragma unroll
    for(int i=0;i<4;i++){
      acca[i][0] += xr_[i]*wa.x; acca[i][1] += xr_[i]*wa.y;
      acca[i][2] += xr_[i]*wa.z; acca[i][3] += xr_[i]*wa.w;
      accb[i][0] += xr_[i]*wb.x; accb[i][1] += xr_[i]*wb.y;
      accb[i][2] += xr_[i]*wb.z; accb[i][3] += xr_[i]*wb.w;
    }
  }
  float4 bva = *(const float4*)&ba[tc*4];
  float4 bvb = *(const float4*)&bb[tc*4];
  #pragma unroll
  for(int i=0;i<4;i++){
    int row = row0 + tr*4 + i;
    if(row < M){
      float4 oa = make_float4(acca[i][0]+bva.x, acca[i][1]+bva.y, acca[i][2]+bva.z, acca[i][3]+bva.w);
      float4 ob = make_float4(accb[i][0]+bvb.x, accb[i][1]+bvb.y, accb[i][2]+bvb.z, accb[i][3]+bvb.w);
      *(float4*)&outa[row*128 + tc*4] = oa;
      *(float4*)&outb[row*128 + tc*4] = ob;
    }
  }
}

// ============================ fused GATv2 edge phase ============================
// One wave per destination node; lane l owns channels 2l,2l+1; 16-lane groups = heads.
// ILP=4 edges/iter; node/csr indices forced scalar via readfirstlane.
__launch_bounds__(256)
__global__ void edge_kernel(const float* __restrict__ xl, const float* __restrict__ xr,
                            const int* __restrict__ off, const int* __restrict__ csr_src,
                            const float2* __restrict__ csr_ea,
                            const float* __restrict__ We, const float* __restrict__ att,
                            const float* __restrict__ bias, const float* __restrict__ res,
                            float* __restrict__ out){
  int wid  = (blockIdx.x*blockDim.x + threadIdx.x) >> 6;
  int lane = threadIdx.x & 63;
  if(wid >= NNODES) return;
  int node = __builtin_amdgcn_readfirstlane(wid);   // provably wave-uniform
  int c0 = lane*2;
  float2 xr2 = *(const float2*)&xr[node*128 + c0];
  float2 xls = *(const float2*)&xl[node*128 + c0];
  float2 av  = *(const float2*)&att[c0];
  float2 w0  = *(const float2*)&We[c0];
  float2 w1  = *(const float2*)&We[128 + c0];

  // self-loop (src=node, ea=0)
  float zx = xls.x + xr2.x; zx = zx > 0.f ? zx : 0.2f*zx;
  float zy = xls.y + xr2.y; zy = zy > 0.f ? zy : 0.2f*zy;
  float m = zx*av.x + zy*av.y;
  #pragma unroll
  for(int o=1;o<16;o<<=1) m += __shfl_xor(m, o, 64);
  float den = 1.f;
  float accx = xls.x, accy = xls.y;

  int e0 = off[node], e1 = off[node+1];
  for(int e=e0; e<e1; e+=4){
    int cnt = e1 - e;                       // scalar
    int   s[4];
    float2 ea[4];
    #pragma unroll
    for(int j=0;j<4;j++){
      if(j < cnt){
        s[j]  = __builtin_amdgcn_readfirstlane(csr_src[e+j]);
        ea[j] = csr_ea[e+j];
      } else {
        s[j] = node; ea[j] = make_float2(0.f,0.f);
      }
    }
    float2 xv[4];
    #pragma unroll
    for(int j=0;j<4;j++) xv[j] = *(const float2*)&xl[(size_t)s[j]*128 + c0];
    float p[4];
    #pragma unroll
    for(int j=0;j<4;j++){
      float z0 = xv[j].x + xr2.x + ea[j].x*w0.x + ea[j].y*w1.x; z0 = z0 > 0.f ? z0 : 0.2f*z0;
      float z1 = xv[j].y + xr2.y + ea[j].x*w0.y + ea[j].y*w1.y; z1 = z1 > 0.f ? z1 : 0.2f*z1;
      p[j] = z0*av.x + z1*av.y;
    }
    #pragma unroll
    for(int o=1;o<16;o<<=1){
      #pragma unroll
      for(int j=0;j<4;j++) p[j] += __shfl_xor(p[j], o, 64);
    }
    #pragma unroll
    for(int j=0;j<4;j++) if(j >= cnt) p[j] = -1e30f;
    float nm = m;
    #pragma unroll
    for(int j=0;j<4;j++) nm = fmaxf(nm, p[j]);
    float sc = __expf(m - nm);
    float pe[4];
    #pragma unroll
    for(int j=0;j<4;j++) pe[j] = __expf(p[j] - nm);
    den  = den*sc  + pe[0]+pe[1]+pe[2]+pe[3];
    accx = accx*sc + pe[0]*xv[0].x + pe[1]*xv[1].x + pe[2]*xv[2].x + pe[3]*xv[3].x;
    accy = accy*sc + pe[0]*xv[0].y + pe[1]*xv[1].y + pe[2]*xv[2].y + pe[3]*xv[3].y;
    m = nm;
  }
  float inv = 1.f/(den + 1e-16f);
  float ox = accx*inv + bias[c0];
  float oy = accy*inv + bias[c0+1];
  ox = ox > 0.f ? ox : 0.f;
  oy = oy > 0.f ? oy : 0.f;
  if(res){ ox += res[node*128 + c0]; oy += res[node*128 + c0 + 1]; }
  *(float2*)&out[node*128 + c0] = make_float2(ox, oy);
}

// ============================ pooling ============================
#define POOL_CHUNK 128
__launch_bounds__(128)
__global__ void pool_kernel(const float* __restrict__ x, const int* __restrict__ batch,
                            float* __restrict__ sums, float* __restrict__ maxv,
                            float* __restrict__ cnt){
  int c = threadIdx.x;
  int n0 = blockIdx.x * POOL_CHUNK;
  if(n0 >= NNODES) return;
  int n1 = n0 + POOL_CHUNK; if(n1 > NNODES) n1 = NNODES;
  int curb = batch[n0];
  float s = 0.f, mx = 0.f;
  float segc = 0.f;
  for(int nd = n0; nd < n1; nd++){
    int b = batch[nd];
    if(b != curb){
      atomicAdd(&sums[curb*128 + c], s);
      atomicMax((int*)&maxv[curb*128 + c], __float_as_int(mx));
      if(c == 0) atomicAdd(&cnt[curb], segc);
      curb = b; s = 0.f; mx = 0.f; segc = 0.f;
    }
    float v = x[nd*128 + c];
    s += v; mx = fmaxf(mx, v); segc += 1.f;
  }
  atomicAdd(&sums[curb*128 + c], s);
  atomicMax((int*)&maxv[curb*128 + c], __float_as_int(mx));
  if(c == 0) atomicAdd(&cnt[curb], segc);
}

// ============================ fused dense trunk + heads ============================
__launch_bounds__(128)
__global__ void fused_dense(const float* __restrict__ sums, const float* __restrict__ maxv,
                            const float* __restrict__ cnt,
                            const float* __restrict__ D1_W, const float* __restrict__ D1_b,
                            const float* __restrict__ D23_W, const float* __restrict__ D23_b,
                            const float* __restrict__ H1_W, const float* __restrict__ H1_b,
                            const float* __restrict__ H2_W, const float* __restrict__ H2_b,
                            const float* __restrict__ H3_W, const float* __restrict__ H3_b,
                            float* __restrict__ out){
  __shared__ float X[256];
  __shared__ float y[128];
  __shared__ float z[128];
  int b = blockIdx.x, t = threadIdx.x;
  float ct = cnt[b]; ct = ct > 1.f ? ct : 1.f;
  X[t]       = sums[b*128 + t] / ct;
  X[128 + t] = maxv[b*128 + t];
  __syncthreads();
  float acc = D1_b[t];
  #pragma unroll 16
  for(int k=0;k<256;k++) acc += X[k]*D1_W[k*128+t];
  y[t] = fmaxf(acc, 0.f);
  __syncthreads();
  acc = D23_b[t];
  #pragma unroll 16
  for(int k=0;k<128;k++) acc += y[k]*D23_W[k*128+t];
  z[t] = fmaxf(acc, 0.f);
  __syncthreads();
  acc = D23_b[128+t];
  #pragma unroll 16
  for(int k=0;k<128;k++) acc += z[k]*D23_W[16384 + k*128+t];
  y[t] = fmaxf(acc, 0.f);
  __syncthreads();
  for(int h=0;h<3;h++){
    acc = H1_b[h*128+t];
    #pragma unroll 16
    for(int k=0;k<128;k++) acc += y[k]*H1_W[h*16384 + k*128+t];
    z[t] = fmaxf(acc, 0.f);
    __syncthreads();
    float v = 0.f;
    if(t < 64){
      float a2 = H2_b[h*64+t];
      #pragma unroll 16
      for(int k=0;k<128;k++) a2 += z[k]*H2_W[h*8192 + k*64+t];
      a2 = fmaxf(a2, 0.f);
      v = a2 * H3_W[h*64 + t];
    }
    #pragma unroll
    for(int o=1;o<64;o<<=1) v += __shfl_xor(v, o, 64);
    if(t == 0){
      float r = v + H3_b[h];
      if(h == 0) r = tanhf(r);
      out[b*3 + h] = r;
    }
    __syncthreads();
  }
}

// ============================ launch ============================
extern "C" void kernel_launch(void* const* d_in, const int* in_sizes, int n_in,
                              void* d_out, int out_size, void* d_ws, size_t ws_size,
                              hipStream_t stream) {
  const float* nodes  = (const float*)d_in[0];
  const int*   eidx   = (const int*)  d_in[1];
  const float* eattr  = (const float*)d_in[2];
  const int*   batch  = (const int*)  d_in[3];
  const float* W0l    = (const float*)d_in[4];
  const float* b0l    = (const float*)d_in[5];
  const float* W0r    = (const float*)d_in[6];
  const float* b0r    = (const float*)d_in[7];
  const float* W0e    = (const float*)d_in[8];
  const float* att0   = (const float*)d_in[9];
  const float* bias0  = (const float*)d_in[10];
  const float* Wl     = (const float*)d_in[11];
  const float* bl     = (const float*)d_in[12];
  const float* Wr     = (const float*)d_in[13];
  const float* br     = (const float*)d_in[14];
  const float* We     = (const float*)d_in[15];
  const float* atts   = (const float*)d_in[16];
  const float* biases = (const float*)d_in[17];
  const float* D1_W   = (const float*)d_in[18];
  const float* D1_b   = (const float*)d_in[19];
  const float* D23_W  = (const float*)d_in[20];
  const float* D23_b  = (const float*)d_in[21];
  const float* H1_W   = (const float*)d_in[22];
  const float* H1_b   = (const float*)d_in[23];
  const float* H2_W   = (const float*)d_in[24];
  const float* H2_b   = (const float*)d_in[25];
  const float* H3_W   = (const float*)d_in[26];
  const float* H3_b   = (const float*)d_in[27];

  // ---- workspace layout ----
  char* ws = (char*)d_ws;
  size_t o = 0;
  auto alloc = [&](size_t bytes)->char*{ char* p = ws + o; o = (o + bytes + 255) & ~(size_t)255; return p; };
  int*    deg     = (int*)   alloc(NNODES*4);
  int*    offs    = (int*)   alloc((NNODES+1)*4);
  int*    cur     = (int*)   alloc(NNODES*4);
  int*    part    = (int*)   alloc(NCHUNK*4);
  int*    csr_src = (int*)   alloc(NEDGES*4);
  float2* csr_ea  = (float2*)alloc(NEDGES*8);
  float*  xl      = (float*) alloc((size_t)NNODES*128*4);
  float*  xr      = (float*) alloc((size_t)NNODES*128*4);
  float*  bufA    = (float*) alloc((size_t)NNODES*128*4);
  float*  bufB    = (float*) alloc((size_t)NNODES*128*4);
  float*  pool    = (float*) alloc((NBATCH*128*2 + NBATCH)*4);
  float*  sums    = pool;
  float*  maxv    = pool + NBATCH*128;
  float*  cnt     = pool + NBATCH*256;
  (void)ws_size; (void)in_sizes; (void)n_in; (void)out_size;

  const int* src = eidx;
  const int* dst = eidx + NEDGES;

  // ---- CSR build ----
  hipMemsetAsync(deg, 0, NNODES*4, stream);
  hipMemsetAsync(pool, 0, (NBATCH*128*2 + NBATCH)*4, stream);
  hist_kernel<<<(NEDGES+255)/256, 256, 0, stream>>>(dst, deg);
  deg_partial<<<NCHUNK, SCAN_BLOCK, 0, stream>>>(deg, part);
  part_scan<<<1, 256, 0, stream>>>(part);
  scan_final<<<NCHUNK, SCAN_BLOCK, 0, stream>>>(deg, part, offs, cur);
  scatter_kernel<<<(NEDGES+255)/256, 256, 0, stream>>>(src, dst, eattr, cur, csr_src, csr_ea);

  // ---- conv0 ----
  gemm_k4_dual<<<(NNODES*128+255)/256, 256, 0, stream>>>(nodes, W0l, b0l, W0r, b0r, xl, xr);
  edge_kernel<<<(NNODES+3)/4, 256, 0, stream>>>(xl, xr, offs, csr_src, csr_ea,
                                                W0e, att0, bias0, nullptr, bufA);

  // ---- 4 skip blocks x 2 convs ----
  const int gemm_grid = (NNODES + 31) / 32;
  for(int blk=0; blk<4; blk++){
    int j = 2*blk;
    gemm_dual<<<gemm_grid, 256, 0, stream>>>(bufA, Wl + (size_t)j*16384, bl + j*128,
                                             Wr + (size_t)j*16384, br + j*128, xl, xr, NNODES);
    edge_kernel<<<(NNODES+3)/4, 256, 0, stream>>>(xl, xr, offs, csr_src, csr_ea,
                                                  We + j*256, atts + j*128, biases + j*128,
                                                  nullptr, bufB);
    j = 2*blk + 1;
    gemm_dual<<<gemm_grid, 256, 0, stream>>>(bufB, Wl + (size_t)j*16384, bl + j*128,
                                             Wr + (size_t)j*16384, br + j*128, xl, xr, NNODES);
    edge_kernel<<<(NNODES+3)/4, 256, 0, stream>>>(xl, xr, offs, csr_src, csr_ea,
                                                  We + j*256, atts + j*128, biases + j*128,
                                                  bufA /*residual*/, bufA);
  }

  // ---- pooling + fused dense trunk/heads ----
  pool_kernel<<<(NNODES + POOL_CHUNK - 1)/POOL_CHUNK, 128, 0, stream>>>(bufA, batch, sums, maxv, cnt);
  fused_dense<<<NBATCH, 128, 0, stream>>>(sums, maxv, cnt,
                                          D1_W, D1_b, D23_W, D23_b,
                                          H1_W, H1_b, H2_W, H2_b, H3_W, H3_b,
                                          (float*)d_out);
}

// Round 10
// 1008.019 us; speedup vs baseline: 1.3404x; 1.2874x over previous
//
#include <hip/hip_runtime.h>
#include <hip/hip_bf16.h>
#include <cmath>

#define NNODES 50000
#define NEDGES 600000
#define NBATCH 50
#define SCAN_BLOCK 256
#define NCHUNK ((NNODES + SCAN_BLOCK - 1) / SCAN_BLOCK)   // 196
#define NSLABS (NNODES/16)                                // 3125 (exact)

typedef __attribute__((ext_vector_type(8))) short bf16x8;
typedef __attribute__((ext_vector_type(4))) float f32x4;

// ============================ CSR build ============================
__global__ void hist_kernel(const int* __restrict__ dst, int* __restrict__ deg){
  int e = blockIdx.x*blockDim.x + threadIdx.x;
  if(e < NEDGES) atomicAdd(&deg[dst[e]], 1);
}

__global__ void deg_partial(const int* __restrict__ deg, int* __restrict__ part){
  __shared__ int red[SCAN_BLOCK];
  int t = threadIdx.x, id = blockIdx.x*SCAN_BLOCK + t;
  red[t] = (id < NNODES) ? deg[id] : 0;
  __syncthreads();
  for(int o = SCAN_BLOCK/2; o > 0; o >>= 1){
    if(t < o) red[t] += red[t+o];
    __syncthreads();
  }
  if(t == 0) part[blockIdx.x] = red[0];
}

__global__ void part_scan(int* __restrict__ part){
  __shared__ int ps[256];
  int t = threadIdx.x;
  int v = (t < NCHUNK) ? part[t] : 0;
  ps[t] = v; __syncthreads();
  for(int o=1;o<256;o<<=1){
    int u = (t>=o) ? ps[t-o] : 0;
    __syncthreads();
    ps[t] += u;
    __syncthreads();
  }
  if(t < NCHUNK) part[t] = ps[t] - v;   // exclusive
}

__global__ void scan_final(const int* __restrict__ deg, const int* __restrict__ part,
                           int* __restrict__ off, int* __restrict__ cur){
  __shared__ int ps[SCAN_BLOCK];
  int t = threadIdx.x, id = blockIdx.x*SCAN_BLOCK + t;
  int v = (id < NNODES) ? deg[id] : 0;
  ps[t] = v; __syncthreads();
  for(int o=1;o<SCAN_BLOCK;o<<=1){
    int u = (t>=o) ? ps[t-o] : 0;
    __syncthreads();
    ps[t] += u;
    __syncthreads();
  }
  int excl = ps[t] - v + part[blockIdx.x];
  if(id < NNODES){ off[id] = excl; cur[id] = excl; }
  if(id == 0) off[NNODES] = NEDGES;
}

__global__ void scatter_kernel(const int* __restrict__ src, const int* __restrict__ dst,
                               const float* __restrict__ ea, int* __restrict__ cur,
                               int* __restrict__ csr_src, float2* __restrict__ csr_ea){
  int e = blockIdx.x*blockDim.x + threadIdx.x;
  if(e >= NEDGES) return;
  int d = dst[e];
  int p = atomicAdd(&cur[d], 1);
  csr_src[p] = src[e];
  csr_ea[p] = make_float2(ea[2*e], ea[2*e+1]);
}

// ============================ conv0 linear (K=4), both outputs ============================
__global__ void gemm_k4_dual(const float* __restrict__ x,
                             const float* __restrict__ Wa, const float* __restrict__ ba,
                             const float* __restrict__ Wb, const float* __restrict__ bb,
                             float* __restrict__ outa, float* __restrict__ outb){
  int idx = blockIdx.x*blockDim.x + threadIdx.x;
  if(idx >= NNODES*128) return;
  int r = idx >> 7, c = idx & 127;
  float4 xv = *(const float4*)&x[r*4];
  float acca = ba[c] + xv.x*Wa[c] + xv.y*Wa[128+c] + xv.z*Wa[256+c] + xv.w*Wa[384+c];
  float accb = bb[c] + xv.x*Wb[c] + xv.y*Wb[128+c] + xv.z*Wb[256+c] + xv.w*Wb[384+c];
  outa[idx] = acca;
  outb[idx] = accb;
}

// ============================ W prep: bf16 hi/lo split + MFMA B-frag swizzle ============================
// B-frag layout for mfma_f32_16x16x32_bf16: lane holds B[k=quad*8+j][n=lane&15].
// Stored so each lane's 8 values are contiguous: idx = ((layer*2+mat)*32 + ct*4+ks)*512 + lane*8 + j.
__global__ void wprep(const float* __restrict__ Wl, const float* __restrict__ Wr,
                      ushort* __restrict__ Bh, ushort* __restrict__ Blo){
  int idx = blockIdx.x*256 + threadIdx.x;   // 8 layers * 2 mats * 32 frags * 64 lanes = 32768
  int lane  = idx & 63;
  int f     = (idx >> 6) & 31;
  int mat   = (idx >> 11) & 1;
  int layer = idx >> 12;
  int ct = f >> 2, ks = f & 3;
  const float* W = (mat ? Wr : Wl) + (size_t)layer*16384;
  int krow = ks*32 + (lane>>4)*8;
  int col  = ct*16 + (lane&15);
  size_t base = ((size_t)(layer*2 + mat)*32 + f)*512 + lane*8;
  #pragma unroll
  for(int j=0;j<8;j++){
    float v = W[(krow+j)*128 + col];
    __hip_bfloat16 h = __float2bfloat16(v);
    __hip_bfloat16 l = __float2bfloat16(v - __bfloat162float(h));
    Bh[base+j]  = *(ushort*)&h;
    Blo[base+j] = *(ushort*)&l;
  }
}

// ============================ dual GEMM via MFMA (bf16x3 split precision) ============================
// x@W = xh@Wh + xh@Wlo + xlo@Wh (dropped xlo@Wlo ~ 2^-18 rel). Wave handles a
// 32-col group (cg), grid-strides over 16-row slabs; B-frags live in registers
// across the slab loop (loaded once). 48 MFMAs per slab (4ks x 2mat x 2ct x 3).
__launch_bounds__(256)
__global__ void gemm_mfma(const ushort* __restrict__ xh, const ushort* __restrict__ xlo,
                          const ushort* __restrict__ Bh, const ushort* __restrict__ Blo,
                          const float* __restrict__ ba, const float* __restrict__ bb,
                          float* __restrict__ outa, float* __restrict__ outb){
  int tid = threadIdx.x;
  int lane = tid & 63;
  int gw = blockIdx.x*4 + (tid>>6);     // global wave id, 0..4095
  int cg = gw & 3;                      // col group: cols [cg*32, cg*32+32)
  int slab0 = gw >> 2;                  // 0..1023
  int m = lane & 15, quad = lane >> 4;

  // B fragments: [mat][term][c][ks], 32 frags x 4 VGPR, persistent
  bf16x8 Bf[2][2][2][4];
  #pragma unroll
  for(int mat=0;mat<2;mat++)
    #pragma unroll
    for(int c=0;c<2;c++)
      #pragma unroll
      for(int ks=0;ks<4;ks++){
        size_t o = ((size_t)mat*32 + (size_t)(cg*2+c)*4 + ks)*512 + lane*8;
        Bf[mat][0][c][ks] = *(const bf16x8*)&Bh[o];
        Bf[mat][1][c][ks] = *(const bf16x8*)&Blo[o];
      }
  float bav[2] = { ba[cg*32 + m], ba[cg*32 + 16 + m] };
  float bbv[2] = { bb[cg*32 + m], bb[cg*32 + 16 + m] };

  for(int slab = slab0; slab < NSLABS; slab += 1024){
    int row0 = slab*16;
    const ushort* pa = xh  + (size_t)(row0+m)*128 + quad*8;
    const ushort* pl = xlo + (size_t)(row0+m)*128 + quad*8;
    f32x4 acc[2][2];
    #pragma unroll
    for(int mat=0;mat<2;mat++)
      #pragma unroll
      for(int c=0;c<2;c++) acc[mat][c] = (f32x4){0.f,0.f,0.f,0.f};
    #pragma unroll
    for(int ks=0;ks<4;ks++){
      bf16x8 Ah = *(const bf16x8*)(pa + ks*32);
      bf16x8 Al = *(const bf16x8*)(pl + ks*32);
      #pragma unroll
      for(int mat=0;mat<2;mat++)
        #pragma unroll
        for(int c=0;c<2;c++){
          acc[mat][c] = __builtin_amdgcn_mfma_f32_16x16x32_bf16(Ah, Bf[mat][0][c][ks], acc[mat][c], 0,0,0);
          acc[mat][c] = __builtin_amdgcn_mfma_f32_16x16x32_bf16(Ah, Bf[mat][1][c][ks], acc[mat][c], 0,0,0);
          acc[mat][c] = __builtin_amdgcn_mfma_f32_16x16x32_bf16(Al, Bf[mat][0][c][ks], acc[mat][c], 0,0,0);
        }
    }
    #pragma unroll
    for(int c=0;c<2;c++){
      int col = cg*32 + c*16 + m;
      #pragma unroll
      for(int r=0;r<4;r++){
        int row = row0 + quad*4 + r;
        outa[(size_t)row*128 + col] = acc[0][c][r] + bav[c];
        outb[(size_t)row*128 + col] = acc[1][c][r] + bbv[c];
      }
    }
  }
}

// ============================ fused GATv2 edge phase ============================
// One wave per destination node; lane l owns channels 2l,2l+1; ILP=4 edges/iter;
// node/csr indices forced scalar via readfirstlane. Emits fp32 out + bf16 hi/lo
// split copies (consumed by next layer's MFMA gemm).
__launch_bounds__(256)
__global__ void edge_kernel(const float* __restrict__ xl, const float* __restrict__ xr,
                            const int* __restrict__ off, const int* __restrict__ csr_src,
                            const float2* __restrict__ csr_ea,
                            const float* __restrict__ We, const float* __restrict__ att,
                            const float* __restrict__ bias, const float* __restrict__ res,
                            float* __restrict__ out,
                            ushort* __restrict__ out_hi, ushort* __restrict__ out_lo){
  int wid  = (blockIdx.x*blockDim.x + threadIdx.x) >> 6;
  int lane = threadIdx.x & 63;
  if(wid >= NNODES) return;
  int node = __builtin_amdgcn_readfirstlane(wid);
  int c0 = lane*2;
  float2 xr2 = *(const float2*)&xr[node*128 + c0];
  float2 xls = *(const float2*)&xl[node*128 + c0];
  float2 av  = *(const float2*)&att[c0];
  float2 w0  = *(const float2*)&We[c0];
  float2 w1  = *(const float2*)&We[128 + c0];

  // self-loop (src=node, ea=0)
  float zx = xls.x + xr2.x; zx = zx > 0.f ? zx : 0.2f*zx;
  float zy = xls.y + xr2.y; zy = zy > 0.f ? zy : 0.2f*zy;
  float m = zx*av.x + zy*av.y;
  #pragma unroll
  for(int o=1;o<16;o<<=1) m += __shfl_xor(m, o, 64);
  float den = 1.f;
  float accx = xls.x, accy = xls.y;

  int e0 = off[node], e1 = off[node+1];
  for(int e=e0; e<e1; e+=4){
    int cnt = e1 - e;
    int   s[4];
    float2 ea[4];
    #pragma unroll
    for(int j=0;j<4;j++){
      if(j < cnt){
        s[j]  = __builtin_amdgcn_readfirstlane(csr_src[e+j]);
        ea[j] = csr_ea[e+j];
      } else {
        s[j] = node; ea[j] = make_float2(0.f,0.f);
      }
    }
    float2 xv[4];
    #pragma unroll
    for(int j=0;j<4;j++) xv[j] = *(const float2*)&xl[(size_t)s[j]*128 + c0];
    float p[4];
    #pragma unroll
    for(int j=0;j<4;j++){
      float z0 = xv[j].x + xr2.x + ea[j].x*w0.x + ea[j].y*w1.x; z0 = z0 > 0.f ? z0 : 0.2f*z0;
      float z1 = xv[j].y + xr2.y + ea[j].x*w0.y + ea[j].y*w1.y; z1 = z1 > 0.f ? z1 : 0.2f*z1;
      p[j] = z0*av.x + z1*av.y;
    }
    #pragma unroll
    for(int o=1;o<16;o<<=1){
      #pragma unroll
      for(int j=0;j<4;j++) p[j] += __shfl_xor(p[j], o, 64);
    }
    #pragma unroll
    for(int j=0;j<4;j++) if(j >= cnt) p[j] = -1e30f;
    float nm = m;
    #pragma unroll
    for(int j=0;j<4;j++) nm = fmaxf(nm, p[j]);
    float sc = __expf(m - nm);
    float pe[4];
    #pragma unroll
    for(int j=0;j<4;j++) pe[j] = __expf(p[j] - nm);
    den  = den*sc  + pe[0]+pe[1]+pe[2]+pe[3];
    accx = accx*sc + pe[0]*xv[0].x + pe[1]*xv[1].x + pe[2]*xv[2].x + pe[3]*xv[3].x;
    accy = accy*sc + pe[0]*xv[0].y + pe[1]*xv[1].y + pe[2]*xv[2].y + pe[3]*xv[3].y;
    m = nm;
  }
  float inv = 1.f/(den + 1e-16f);
  float ox = accx*inv + bias[c0];
  float oy = accy*inv + bias[c0+1];
  ox = ox > 0.f ? ox : 0.f;
  oy = oy > 0.f ? oy : 0.f;
  if(res){ ox += res[node*128 + c0]; oy += res[node*128 + c0 + 1]; }
  *(float2*)&out[node*128 + c0] = make_float2(ox, oy);
  // bf16 hi/lo split for next layer's MFMA gemm
  __hip_bfloat16 hx = __float2bfloat16(ox);
  __hip_bfloat16 hy = __float2bfloat16(oy);
  __hip_bfloat16 lx = __float2bfloat16(ox - __bfloat162float(hx));
  __hip_bfloat16 ly = __float2bfloat16(oy - __bfloat162float(hy));
  *(ushort2*)&out_hi[node*128 + c0] = make_ushort2(*(ushort*)&hx, *(ushort*)&hy);
  *(ushort2*)&out_lo[node*128 + c0] = make_ushort2(*(ushort*)&lx, *(ushort*)&ly);
}

// ============================ pooling ============================
#define POOL_CHUNK 128
__launch_bounds__(128)
__global__ void pool_kernel(const float* __restrict__ x, const int* __restrict__ batch,
                            float* __restrict__ sums, float* __restrict__ maxv,
                            float* __restrict__ cnt){
  int c = threadIdx.x;
  int n0 = blockIdx.x * POOL_CHUNK;
  if(n0 >= NNODES) return;
  int n1 = n0 + POOL_CHUNK; if(n1 > NNODES) n1 = NNODES;
  int curb = batch[n0];
  float s = 0.f, mx = 0.f;
  float segc = 0.f;
  for(int nd = n0; nd < n1; nd++){
    int b = batch[nd];
    if(b != curb){
      atomicAdd(&sums[curb*128 + c], s);
      atomicMax((int*)&maxv[curb*128 + c], __float_as_int(mx));
      if(c == 0) atomicAdd(&cnt[curb], segc);
      curb = b; s = 0.f; mx = 0.f; segc = 0.f;
    }
    float v = x[nd*128 + c];
    s += v; mx = fmaxf(mx, v); segc += 1.f;
  }
  atomicAdd(&sums[curb*128 + c], s);
  atomicMax((int*)&maxv[curb*128 + c], __float_as_int(mx));
  if(c == 0) atomicAdd(&cnt[curb], segc);
}

// ============================ fused dense trunk + heads ============================
__launch_bounds__(128)
__global__ void fused_dense(const float* __restrict__ sums, const float* __restrict__ maxv,
                            const float* __restrict__ cnt,
                            const float* __restrict__ D1_W, const float* __restrict__ D1_b,
                            const float* __restrict__ D23_W, const float* __restrict__ D23_b,
                            const float* __restrict__ H1_W, const float* __restrict__ H1_b,
                            const float* __restrict__ H2_W, const float* __restrict__ H2_b,
                            const float* __restrict__ H3_W, const float* __restrict__ H3_b,
                            float* __restrict__ out){
  __shared__ float X[256];
  __shared__ float y[128];
  __shared__ float z[128];
  int b = blockIdx.x, t = threadIdx.x;
  float ct = cnt[b]; ct = ct > 1.f ? ct : 1.f;
  X[t]       = sums[b*128 + t] / ct;
  X[128 + t] = maxv[b*128 + t];
  __syncthreads();
  float acc = D1_b[t];
  #pragma unroll 16
  for(int k=0;k<256;k++) acc += X[k]*D1_W[k*128+t];
  y[t] = fmaxf(acc, 0.f);
  __syncthreads();
  acc = D23_b[t];
  #pragma unroll 16
  for(int k=0;k<128;k++) acc += y[k]*D23_W[k*128+t];
  z[t] = fmaxf(acc, 0.f);
  __syncthreads();
  acc = D23_b[128+t];
  #pragma unroll 16
  for(int k=0;k<128;k++) acc += z[k]*D23_W[16384 + k*128+t];
  y[t] = fmaxf(acc, 0.f);
  __syncthreads();
  for(int h=0;h<3;h++){
    acc = H1_b[h*128+t];
    #pragma unroll 16
    for(int k=0;k<128;k++) acc += y[k]*H1_W[h*16384 + k*128+t];
    z[t] = fmaxf(acc, 0.f);
    __syncthreads();
    float v = 0.f;
    if(t < 64){
      float a2 = H2_b[h*64+t];
      #pragma unroll 16
      for(int k=0;k<128;k++) a2 += z[k]*H2_W[h*8192 + k*64+t];
      a2 = fmaxf(a2, 0.f);
      v = a2 * H3_W[h*64 + t];
    }
    #pragma unroll
    for(int o=1;o<64;o<<=1) v += __shfl_xor(v, o, 64);
    if(t == 0){
      float r = v + H3_b[h];
      if(h == 0) r = tanhf(r);
      out[b*3 + h] = r;
    }
    __syncthreads();
  }
}

// ============================ launch ============================
extern "C" void kernel_launch(void* const* d_in, const int* in_sizes, int n_in,
                              void* d_out, int out_size, void* d_ws, size_t ws_size,
                              hipStream_t stream) {
  const float* nodes  = (const float*)d_in[0];
  const int*   eidx   = (const int*)  d_in[1];
  const float* eattr  = (const float*)d_in[2];
  const int*   batch  = (const int*)  d_in[3];
  const float* W0l    = (const float*)d_in[4];
  const float* b0l    = (const float*)d_in[5];
  const float* W0r    = (const float*)d_in[6];
  const float* b0r    = (const float*)d_in[7];
  const float* W0e    = (const float*)d_in[8];
  const float* att0   = (const float*)d_in[9];
  const float* bias0  = (const float*)d_in[10];
  const float* Wl     = (const float*)d_in[11];
  const float* bl     = (const float*)d_in[12];
  const float* Wr     = (const float*)d_in[13];
  const float* br     = (const float*)d_in[14];
  const float* We     = (const float*)d_in[15];
  const float* atts   = (const float*)d_in[16];
  const float* biases = (const float*)d_in[17];
  const float* D1_W   = (const float*)d_in[18];
  const float* D1_b   = (const float*)d_in[19];
  const float* D23_W  = (const float*)d_in[20];
  const float* D23_b  = (const float*)d_in[21];
  const float* H1_W   = (const float*)d_in[22];
  const float* H1_b   = (const float*)d_in[23];
  const float* H2_W   = (const float*)d_in[24];
  const float* H2_b   = (const float*)d_in[25];
  const float* H3_W   = (const float*)d_in[26];
  const float* H3_b   = (const float*)d_in[27];

  // ---- workspace layout ----
  char* ws = (char*)d_ws;
  size_t o = 0;
  auto alloc = [&](size_t bytes)->char*{ char* p = ws + o; o = (o + bytes + 255) & ~(size_t)255; return p; };
  int*    deg     = (int*)   alloc(NNODES*4);
  int*    offs    = (int*)   alloc((NNODES+1)*4);
  int*    cur     = (int*)   alloc(NNODES*4);
  int*    part    = (int*)   alloc(NCHUNK*4);
  int*    csr_src = (int*)   alloc(NEDGES*4);
  float2* csr_ea  = (float2*)alloc(NEDGES*8);
  float*  xl      = (float*) alloc((size_t)NNODES*128*4);
  float*  xr      = (float*) alloc((size_t)NNODES*128*4);
  float*  bufA    = (float*) alloc((size_t)NNODES*128*4);
  float*  bufB    = (float*) alloc((size_t)NNODES*128*4);
  ushort* bufA_hi = (ushort*)alloc((size_t)NNODES*128*2);
  ushort* bufA_lo = (ushort*)alloc((size_t)NNODES*128*2);
  ushort* bufB_hi = (ushort*)alloc((size_t)NNODES*128*2);
  ushort* bufB_lo = (ushort*)alloc((size_t)NNODES*128*2);
  ushort* Bh      = (ushort*)alloc((size_t)8*2*32*512*2);   // swizzled W hi
  ushort* Blo     = (ushort*)alloc((size_t)8*2*32*512*2);   // swizzled W lo
  float*  pool    = (float*) alloc((NBATCH*128*2 + NBATCH)*4);
  float*  sums    = pool;
  float*  maxv    = pool + NBATCH*128;
  float*  cnt     = pool + NBATCH*256;
  (void)ws_size; (void)in_sizes; (void)n_in; (void)out_size;

  const int* src = eidx;
  const int* dst = eidx + NEDGES;

  // ---- CSR build + W prep ----
  hipMemsetAsync(deg, 0, NNODES*4, stream);
  hipMemsetAsync(pool, 0, (NBATCH*128*2 + NBATCH)*4, stream);
  hist_kernel<<<(NEDGES+255)/256, 256, 0, stream>>>(dst, deg);
  deg_partial<<<NCHUNK, SCAN_BLOCK, 0, stream>>>(deg, part);
  part_scan<<<1, 256, 0, stream>>>(part);
  scan_final<<<NCHUNK, SCAN_BLOCK, 0, stream>>>(deg, part, offs, cur);
  scatter_kernel<<<(NEDGES+255)/256, 256, 0, stream>>>(src, dst, eattr, cur, csr_src, csr_ea);
  wprep<<<128, 256, 0, stream>>>(Wl, Wr, Bh, Blo);

  // ---- conv0 ----
  gemm_k4_dual<<<(NNODES*128+255)/256, 256, 0, stream>>>(nodes, W0l, b0l, W0r, b0r, xl, xr);
  edge_kernel<<<(NNODES+3)/4, 256, 0, stream>>>(xl, xr, offs, csr_src, csr_ea,
                                                W0e, att0, bias0, nullptr, bufA, bufA_hi, bufA_lo);

  // ---- 4 skip blocks x 2 convs ----
  const size_t wstride = (size_t)2*32*512;   // per-layer stride in swizzled W
  for(int blk=0; blk<4; blk++){
    int j = 2*blk;
    gemm_mfma<<<1024, 256, 0, stream>>>(bufA_hi, bufA_lo, Bh + (size_t)j*wstride, Blo + (size_t)j*wstride,
                                        bl + j*128, br + j*128, xl, xr);
    edge_kernel<<<(NNODES+3)/4, 256, 0, stream>>>(xl, xr, offs, csr_src, csr_ea,
                                                  We + j*256, atts + j*128, biases + j*128,
                                                  nullptr, bufB, bufB_hi, bufB_lo);
    j = 2*blk + 1;
    gemm_mfma<<<1024, 256, 0, stream>>>(bufB_hi, bufB_lo, Bh + (size_t)j*wstride, Blo + (size_t)j*wstride,
                                        bl + j*128, br + j*128, xl, xr);
    edge_kernel<<<(NNODES+3)/4, 256, 0, stream>>>(xl, xr, offs, csr_src, csr_ea,
                                                  We + j*256, atts + j*128, biases + j*128,
                                                  bufA /*residual*/, bufA, bufA_hi, bufA_lo);
  }

  // ---- pooling + fused dense trunk/heads ----
  pool_kernel<<<(NNODES + POOL_CHUNK - 1)/POOL_CHUNK, 128, 0, stream>>>(bufA, batch, sums, maxv, cnt);
  fused_dense<<<NBATCH, 128, 0, stream>>>(sums, maxv, cnt,
                                          D1_W, D1_b, D23_W, D23_b,
                                          H1_W, H1_b, H2_W, H2_b, H3_W, H3_b,
                                          (float*)d_out);
}

// Round 11
// 932.260 us; speedup vs baseline: 1.4493x; 1.0813x over previous
//
#include <hip/hip_runtime.h>
#include <hip/hip_bf16.h>
#include <cmath>

#define NNODES 50000
#define NEDGES 600000
#define NBATCH 50
#define SCAN_BLOCK 256
#define NCHUNK ((NNODES + SCAN_BLOCK - 1) / SCAN_BLOCK)   // 196
#define NSLABS (NNODES/16)                                // 3125 (exact)

typedef __attribute__((ext_vector_type(8))) short bf16x8;
typedef __attribute__((ext_vector_type(4))) float f32x4;

__device__ __forceinline__ float bf2f(ushort u){ return __uint_as_float(((unsigned)u) << 16); }

// ============================ CSR build ============================
__global__ void hist_kernel(const int* __restrict__ dst, int* __restrict__ deg){
  int e = blockIdx.x*blockDim.x + threadIdx.x;
  if(e < NEDGES) atomicAdd(&deg[dst[e]], 1);
}

__global__ void deg_partial(const int* __restrict__ deg, int* __restrict__ part){
  __shared__ int red[SCAN_BLOCK];
  int t = threadIdx.x, id = blockIdx.x*SCAN_BLOCK + t;
  red[t] = (id < NNODES) ? deg[id] : 0;
  __syncthreads();
  for(int o = SCAN_BLOCK/2; o > 0; o >>= 1){
    if(t < o) red[t] += red[t+o];
    __syncthreads();
  }
  if(t == 0) part[blockIdx.x] = red[0];
}

__global__ void part_scan(int* __restrict__ part){
  __shared__ int ps[256];
  int t = threadIdx.x;
  int v = (t < NCHUNK) ? part[t] : 0;
  ps[t] = v; __syncthreads();
  for(int o=1;o<256;o<<=1){
    int u = (t>=o) ? ps[t-o] : 0;
    __syncthreads();
    ps[t] += u;
    __syncthreads();
  }
  if(t < NCHUNK) part[t] = ps[t] - v;   // exclusive
}

__global__ void scan_final(const int* __restrict__ deg, const int* __restrict__ part,
                           int* __restrict__ off, int* __restrict__ cur){
  __shared__ int ps[SCAN_BLOCK];
  int t = threadIdx.x, id = blockIdx.x*SCAN_BLOCK + t;
  int v = (id < NNODES) ? deg[id] : 0;
  ps[t] = v; __syncthreads();
  for(int o=1;o<SCAN_BLOCK;o<<=1){
    int u = (t>=o) ? ps[t-o] : 0;
    __syncthreads();
    ps[t] += u;
    __syncthreads();
  }
  int excl = ps[t] - v + part[blockIdx.x];
  if(id < NNODES){ off[id] = excl; cur[id] = excl; }
  if(id == 0) off[NNODES] = NEDGES;
}

__global__ void scatter_kernel(const int* __restrict__ src, const int* __restrict__ dst,
                               const float* __restrict__ ea, int* __restrict__ cur,
                               int* __restrict__ csr_src, float2* __restrict__ csr_ea){
  int e = blockIdx.x*blockDim.x + threadIdx.x;
  if(e >= NEDGES) return;
  int d = dst[e];
  int p = atomicAdd(&cur[d], 1);
  csr_src[p] = src[e];
  csr_ea[p] = make_float2(ea[2*e], ea[2*e+1]);
}

// ============================ conv0 linear (K=4) ============================
// xl emitted as bf16 (edge gathers bf16 rows), xr as fp32.
__global__ void gemm_k4_dual(const float* __restrict__ x,
                             const float* __restrict__ Wa, const float* __restrict__ ba,
                             const float* __restrict__ Wb, const float* __restrict__ bb,
                             ushort* __restrict__ outa_bf, float* __restrict__ outb){
  int idx = blockIdx.x*blockDim.x + threadIdx.x;
  if(idx >= NNODES*128) return;
  int r = idx >> 7, c = idx & 127;
  float4 xv = *(const float4*)&x[r*4];
  float acca = ba[c] + xv.x*Wa[c] + xv.y*Wa[128+c] + xv.z*Wa[256+c] + xv.w*Wa[384+c];
  float accb = bb[c] + xv.x*Wb[c] + xv.y*Wb[128+c] + xv.z*Wb[256+c] + xv.w*Wb[384+c];
  __hip_bfloat16 h = __float2bfloat16(acca);
  outa_bf[idx] = *(ushort*)&h;
  outb[idx] = accb;
}

// ============================ W prep: bf16 hi/lo split + MFMA B-frag swizzle ============================
__global__ void wprep(const float* __restrict__ Wl, const float* __restrict__ Wr,
                      ushort* __restrict__ Bh, ushort* __restrict__ Blo){
  int idx = blockIdx.x*256 + threadIdx.x;   // 8 layers * 2 mats * 32 frags * 64 lanes = 32768
  int lane  = idx & 63;
  int f     = (idx >> 6) & 31;
  int mat   = (idx >> 11) & 1;
  int layer = idx >> 12;
  int ct = f >> 2, ks = f & 3;
  const float* W = (mat ? Wr : Wl) + (size_t)layer*16384;
  int krow = ks*32 + (lane>>4)*8;
  int col  = ct*16 + (lane&15);
  size_t base = ((size_t)(layer*2 + mat)*32 + f)*512 + lane*8;
  #pragma unroll
  for(int j=0;j<8;j++){
    float v = W[(krow+j)*128 + col];
    __hip_bfloat16 h = __float2bfloat16(v);
    __hip_bfloat16 l = __float2bfloat16(v - __bfloat162float(h));
    Bh[base+j]  = *(ushort*)&h;
    Blo[base+j] = *(ushort*)&l;
  }
}

// ============================ dual GEMM via MFMA (bf16x3 split precision) ============================
// xl output as bf16 (for edge gather), xr as fp32.
__launch_bounds__(256)
__global__ void gemm_mfma(const ushort* __restrict__ xh, const ushort* __restrict__ xlo,
                          const ushort* __restrict__ Bh, const ushort* __restrict__ Blo,
                          const float* __restrict__ ba, const float* __restrict__ bb,
                          ushort* __restrict__ outa_bf, float* __restrict__ outb){
  int tid = threadIdx.x;
  int lane = tid & 63;
  int gw = blockIdx.x*4 + (tid>>6);     // global wave id, 0..4095
  int cg = gw & 3;                      // col group: cols [cg*32, cg*32+32)
  int slab0 = gw >> 2;                  // 0..1023
  int m = lane & 15, quad = lane >> 4;

  bf16x8 Bf[2][2][2][4];
  #pragma unroll
  for(int mat=0;mat<2;mat++)
    #pragma unroll
    for(int c=0;c<2;c++)
      #pragma unroll
      for(int ks=0;ks<4;ks++){
        size_t o = ((size_t)mat*32 + (size_t)(cg*2+c)*4 + ks)*512 + lane*8;
        Bf[mat][0][c][ks] = *(const bf16x8*)&Bh[o];
        Bf[mat][1][c][ks] = *(const bf16x8*)&Blo[o];
      }
  float bav[2] = { ba[cg*32 + m], ba[cg*32 + 16 + m] };
  float bbv[2] = { bb[cg*32 + m], bb[cg*32 + 16 + m] };

  for(int slab = slab0; slab < NSLABS; slab += 1024){
    int row0 = slab*16;
    const ushort* pa = xh  + (size_t)(row0+m)*128 + quad*8;
    const ushort* pl = xlo + (size_t)(row0+m)*128 + quad*8;
    f32x4 acc[2][2];
    #pragma unroll
    for(int mat=0;mat<2;mat++)
      #pragma unroll
      for(int c=0;c<2;c++) acc[mat][c] = (f32x4){0.f,0.f,0.f,0.f};
    #pragma unroll
    for(int ks=0;ks<4;ks++){
      bf16x8 Ah = *(const bf16x8*)(pa + ks*32);
      bf16x8 Al = *(const bf16x8*)(pl + ks*32);
      #pragma unroll
      for(int mat=0;mat<2;mat++)
        #pragma unroll
        for(int c=0;c<2;c++){
          acc[mat][c] = __builtin_amdgcn_mfma_f32_16x16x32_bf16(Ah, Bf[mat][0][c][ks], acc[mat][c], 0,0,0);
          acc[mat][c] = __builtin_amdgcn_mfma_f32_16x16x32_bf16(Ah, Bf[mat][1][c][ks], acc[mat][c], 0,0,0);
          acc[mat][c] = __builtin_amdgcn_mfma_f32_16x16x32_bf16(Al, Bf[mat][0][c][ks], acc[mat][c], 0,0,0);
        }
    }
    #pragma unroll
    for(int c=0;c<2;c++){
      int col = cg*32 + c*16 + m;
      #pragma unroll
      for(int r=0;r<4;r++){
        int row = row0 + quad*4 + r;
        float va = acc[0][c][r] + bav[c];
        __hip_bfloat16 h = __float2bfloat16(va);
        outa_bf[(size_t)row*128 + col] = *(ushort*)&h;
        outb[(size_t)row*128 + col] = acc[1][c][r] + bbv[c];
      }
    }
  }
}

// ============================ fused GATv2 edge phase ============================
// Gathers bf16 xl rows (4 B/lane instead of 8 -> halves gather traffic).
// One wave per destination node; ILP=4 edges/iter; indices scalar via readfirstlane.
__launch_bounds__(256)
__global__ void edge_kernel(const ushort* __restrict__ xlb, const float* __restrict__ xr,
                            const int* __restrict__ off, const int* __restrict__ csr_src,
                            const float2* __restrict__ csr_ea,
                            const float* __restrict__ We, const float* __restrict__ att,
                            const float* __restrict__ bias, const float* __restrict__ res,
                            float* __restrict__ out,
                            ushort* __restrict__ out_hi, ushort* __restrict__ out_lo){
  int wid  = (blockIdx.x*blockDim.x + threadIdx.x) >> 6;
  int lane = threadIdx.x & 63;
  if(wid >= NNODES) return;
  int node = __builtin_amdgcn_readfirstlane(wid);
  int c0 = lane*2;
  float2 xr2 = *(const float2*)&xr[node*128 + c0];
  ushort2 su = *(const ushort2*)&xlb[node*128 + c0];
  float2 xls = make_float2(bf2f(su.x), bf2f(su.y));
  float2 av  = *(const float2*)&att[c0];
  float2 w0  = *(const float2*)&We[c0];
  float2 w1  = *(const float2*)&We[128 + c0];

  // self-loop (src=node, ea=0)
  float zx = xls.x + xr2.x; zx = zx > 0.f ? zx : 0.2f*zx;
  float zy = xls.y + xr2.y; zy = zy > 0.f ? zy : 0.2f*zy;
  float m = zx*av.x + zy*av.y;
  #pragma unroll
  for(int o=1;o<16;o<<=1) m += __shfl_xor(m, o, 64);
  float den = 1.f;
  float accx = xls.x, accy = xls.y;

  int e0 = off[node], e1 = off[node+1];
  for(int e=e0; e<e1; e+=4){
    int cnt = e1 - e;
    int   s[4];
    float2 ea[4];
    #pragma unroll
    for(int j=0;j<4;j++){
      if(j < cnt){
        s[j]  = __builtin_amdgcn_readfirstlane(csr_src[e+j]);
        ea[j] = csr_ea[e+j];
      } else {
        s[j] = node; ea[j] = make_float2(0.f,0.f);
      }
    }
    float2 xv[4];
    #pragma unroll
    for(int j=0;j<4;j++){
      ushort2 u = *(const ushort2*)&xlb[(size_t)s[j]*128 + c0];
      xv[j] = make_float2(bf2f(u.x), bf2f(u.y));
    }
    float p[4];
    #pragma unroll
    for(int j=0;j<4;j++){
      float z0 = xv[j].x + xr2.x + ea[j].x*w0.x + ea[j].y*w1.x; z0 = z0 > 0.f ? z0 : 0.2f*z0;
      float z1 = xv[j].y + xr2.y + ea[j].x*w0.y + ea[j].y*w1.y; z1 = z1 > 0.f ? z1 : 0.2f*z1;
      p[j] = z0*av.x + z1*av.y;
    }
    #pragma unroll
    for(int o=1;o<16;o<<=1){
      #pragma unroll
      for(int j=0;j<4;j++) p[j] += __shfl_xor(p[j], o, 64);
    }
    #pragma unroll
    for(int j=0;j<4;j++) if(j >= cnt) p[j] = -1e30f;
    float nm = m;
    #pragma unroll
    for(int j=0;j<4;j++) nm = fmaxf(nm, p[j]);
    float sc = __expf(m - nm);
    float pe[4];
    #pragma unroll
    for(int j=0;j<4;j++) pe[j] = __expf(p[j] - nm);
    den  = den*sc  + pe[0]+pe[1]+pe[2]+pe[3];
    accx = accx*sc + pe[0]*xv[0].x + pe[1]*xv[1].x + pe[2]*xv[2].x + pe[3]*xv[3].x;
    accy = accy*sc + pe[0]*xv[0].y + pe[1]*xv[1].y + pe[2]*xv[2].y + pe[3]*xv[3].y;
    m = nm;
  }
  float inv = 1.f/(den + 1e-16f);
  float ox = accx*inv + bias[c0];
  float oy = accy*inv + bias[c0+1];
  ox = ox > 0.f ? ox : 0.f;
  oy = oy > 0.f ? oy : 0.f;
  if(res){ ox += res[node*128 + c0]; oy += res[node*128 + c0 + 1]; }
  *(float2*)&out[node*128 + c0] = make_float2(ox, oy);
  // bf16 hi/lo split for next layer's MFMA gemm
  __hip_bfloat16 hx = __float2bfloat16(ox);
  __hip_bfloat16 hy = __float2bfloat16(oy);
  __hip_bfloat16 lx = __float2bfloat16(ox - __bfloat162float(hx));
  __hip_bfloat16 ly = __float2bfloat16(oy - __bfloat162float(hy));
  *(ushort2*)&out_hi[node*128 + c0] = make_ushort2(*(ushort*)&hx, *(ushort*)&hy);
  *(ushort2*)&out_lo[node*128 + c0] = make_ushort2(*(ushort*)&lx, *(ushort*)&ly);
}

// ============================ pooling ============================
#define POOL_CHUNK 128
__launch_bounds__(128)
__global__ void pool_kernel(const float* __restrict__ x, const int* __restrict__ batch,
                            float* __restrict__ sums, float* __restrict__ maxv,
                            float* __restrict__ cnt){
  int c = threadIdx.x;
  int n0 = blockIdx.x * POOL_CHUNK;
  if(n0 >= NNODES) return;
  int n1 = n0 + POOL_CHUNK; if(n1 > NNODES) n1 = NNODES;
  int curb = batch[n0];
  float s = 0.f, mx = 0.f;
  float segc = 0.f;
  for(int nd = n0; nd < n1; nd++){
    int b = batch[nd];
    if(b != curb){
      atomicAdd(&sums[curb*128 + c], s);
      atomicMax((int*)&maxv[curb*128 + c], __float_as_int(mx));
      if(c == 0) atomicAdd(&cnt[curb], segc);
      curb = b; s = 0.f; mx = 0.f; segc = 0.f;
    }
    float v = x[nd*128 + c];
    s += v; mx = fmaxf(mx, v); segc += 1.f;
  }
  atomicAdd(&sums[curb*128 + c], s);
  atomicMax((int*)&maxv[curb*128 + c], __float_as_int(mx));
  if(c == 0) atomicAdd(&cnt[curb], segc);
}

// ============================ fused dense trunk + heads ============================
__launch_bounds__(128)
__global__ void fused_dense(const float* __restrict__ sums, const float* __restrict__ maxv,
                            const float* __restrict__ cnt,
                            const float* __restrict__ D1_W, const float* __restrict__ D1_b,
                            const float* __restrict__ D23_W, const float* __restrict__ D23_b,
                            const float* __restrict__ H1_W, const float* __restrict__ H1_b,
                            const float* __restrict__ H2_W, const float* __restrict__ H2_b,
                            const float* __restrict__ H3_W, const float* __restrict__ H3_b,
                            float* __restrict__ out){
  __shared__ float X[256];
  __shared__ float y[128];
  __shared__ float z[128];
  int b = blockIdx.x, t = threadIdx.x;
  float ct = cnt[b]; ct = ct > 1.f ? ct : 1.f;
  X[t]       = sums[b*128 + t] / ct;
  X[128 + t] = maxv[b*128 + t];
  __syncthreads();
  float acc = D1_b[t];
  #pragma unroll 16
  for(int k=0;k<256;k++) acc += X[k]*D1_W[k*128+t];
  y[t] = fmaxf(acc, 0.f);
  __syncthreads();
  acc = D23_b[t];
  #pragma unroll 16
  for(int k=0;k<128;k++) acc += y[k]*D23_W[k*128+t];
  z[t] = fmaxf(acc, 0.f);
  __syncthreads();
  acc = D23_b[128+t];
  #pragma unroll 16
  for(int k=0;k<128;k++) acc += z[k]*D23_W[16384 + k*128+t];
  y[t] = fmaxf(acc, 0.f);
  __syncthreads();
  for(int h=0;h<3;h++){
    acc = H1_b[h*128+t];
    #pragma unroll 16
    for(int k=0;k<128;k++) acc += y[k]*H1_W[h*16384 + k*128+t];
    z[t] = fmaxf(acc, 0.f);
    __syncthreads();
    float v = 0.f;
    if(t < 64){
      float a2 = H2_b[h*64+t];
      #pragma unroll 16
      for(int k=0;k<128;k++) a2 += z[k]*H2_W[h*8192 + k*64+t];
      a2 = fmaxf(a2, 0.f);
      v = a2 * H3_W[h*64 + t];
    }
    #pragma unroll
    for(int o=1;o<64;o<<=1) v += __shfl_xor(v, o, 64);
    if(t == 0){
      float r = v + H3_b[h];
      if(h == 0) r = tanhf(r);
      out[b*3 + h] = r;
    }
    __syncthreads();
  }
}

// ============================ launch ============================
extern "C" void kernel_launch(void* const* d_in, const int* in_sizes, int n_in,
                              void* d_out, int out_size, void* d_ws, size_t ws_size,
                              hipStream_t stream) {
  const float* nodes  = (const float*)d_in[0];
  const int*   eidx   = (const int*)  d_in[1];
  const float* eattr  = (const float*)d_in[2];
  const int*   batch  = (const int*)  d_in[3];
  const float* W0l    = (const float*)d_in[4];
  const float* b0l    = (const float*)d_in[5];
  const float* W0r    = (const float*)d_in[6];
  const float* b0r    = (const float*)d_in[7];
  const float* W0e    = (const float*)d_in[8];
  const float* att0   = (const float*)d_in[9];
  const float* bias0  = (const float*)d_in[10];
  const float* Wl     = (const float*)d_in[11];
  const float* bl     = (const float*)d_in[12];
  const float* Wr     = (const float*)d_in[13];
  const float* br     = (const float*)d_in[14];
  const float* We     = (const float*)d_in[15];
  const float* atts   = (const float*)d_in[16];
  const float* biases = (const float*)d_in[17];
  const float* D1_W   = (const float*)d_in[18];
  const float* D1_b   = (const float*)d_in[19];
  const float* D23_W  = (const float*)d_in[20];
  const float* D23_b  = (const float*)d_in[21];
  const float* H1_W   = (const float*)d_in[22];
  const float* H1_b   = (const float*)d_in[23];
  const float* H2_W   = (const float*)d_in[24];
  const float* H2_b   = (const float*)d_in[25];
  const float* H3_W   = (const float*)d_in[26];
  const float* H3_b   = (const float*)d_in[27];

  // ---- workspace layout ----
  char* ws = (char*)d_ws;
  size_t o = 0;
  auto alloc = [&](size_t bytes)->char*{ char* p = ws + o; o = (o + bytes + 255) & ~(size_t)255; return p; };
  int*    deg     = (int*)   alloc(NNODES*4);
  int*    offs    = (int*)   alloc((NNODES+1)*4);
  int*    cur     = (int*)   alloc(NNODES*4);
  int*    part    = (int*)   alloc(NCHUNK*4);
  int*    csr_src = (int*)   alloc(NEDGES*4);
  float2* csr_ea  = (float2*)alloc(NEDGES*8);
  ushort* xlb     = (ushort*)alloc((size_t)NNODES*128*2);   // bf16 xl (gather target)
  float*  xr      = (float*) alloc((size_t)NNODES*128*4);
  float*  bufA    = (float*) alloc((size_t)NNODES*128*4);
  float*  bufB    = (float*) alloc((size_t)NNODES*128*4);
  ushort* bufA_hi = (ushort*)alloc((size_t)NNODES*128*2);
  ushort* bufA_lo = (ushort*)alloc((size_t)NNODES*128*2);
  ushort* bufB_hi = (ushort*)alloc((size_t)NNODES*128*2);
  ushort* bufB_lo = (ushort*)alloc((size_t)NNODES*128*2);
  ushort* Bh      = (ushort*)alloc((size_t)8*2*32*512*2);   // swizzled W hi
  ushort* Blo     = (ushort*)alloc((size_t)8*2*32*512*2);   // swizzled W lo
  float*  pool    = (float*) alloc((NBATCH*128*2 + NBATCH)*4);
  float*  sums    = pool;
  float*  maxv    = pool + NBATCH*128;
  float*  cnt     = pool + NBATCH*256;
  (void)ws_size; (void)in_sizes; (void)n_in; (void)out_size;

  const int* src = eidx;
  const int* dst = eidx + NEDGES;

  // ---- CSR build + W prep ----
  hipMemsetAsync(deg, 0, NNODES*4, stream);
  hipMemsetAsync(pool, 0, (NBATCH*128*2 + NBATCH)*4, stream);
  hist_kernel<<<(NEDGES+255)/256, 256, 0, stream>>>(dst, deg);
  deg_partial<<<NCHUNK, SCAN_BLOCK, 0, stream>>>(deg, part);
  part_scan<<<1, 256, 0, stream>>>(part);
  scan_final<<<NCHUNK, SCAN_BLOCK, 0, stream>>>(deg, part, offs, cur);
  scatter_kernel<<<(NEDGES+255)/256, 256, 0, stream>>>(src, dst, eattr, cur, csr_src, csr_ea);
  wprep<<<128, 256, 0, stream>>>(Wl, Wr, Bh, Blo);

  // ---- conv0 ----
  gemm_k4_dual<<<(NNODES*128+255)/256, 256, 0, stream>>>(nodes, W0l, b0l, W0r, b0r, xlb, xr);
  edge_kernel<<<(NNODES+3)/4, 256, 0, stream>>>(xlb, xr, offs, csr_src, csr_ea,
                                                W0e, att0, bias0, nullptr, bufA, bufA_hi, bufA_lo);

  // ---- 4 skip blocks x 2 convs ----
  const size_t wstride = (size_t)2*32*512;   // per-layer stride in swizzled W
  for(int blk=0; blk<4; blk++){
    int j = 2*blk;
    gemm_mfma<<<1024, 256, 0, stream>>>(bufA_hi, bufA_lo, Bh + (size_t)j*wstride, Blo + (size_t)j*wstride,
                                        bl + j*128, br + j*128, xlb, xr);
    edge_kernel<<<(NNODES+3)/4, 256, 0, stream>>>(xlb, xr, offs, csr_src, csr_ea,
                                                  We + j*256, atts + j*128, biases + j*128,
                                                  nullptr, bufB, bufB_hi, bufB_lo);
    j = 2*blk + 1;
    gemm_mfma<<<1024, 256, 0, stream>>>(bufB_hi, bufB_lo, Bh + (size_t)j*wstride, Blo + (size_t)j*wstride,
                                        bl + j*128, br + j*128, xlb, xr);
    edge_kernel<<<(NNODES+3)/4, 256, 0, stream>>>(xlb, xr, offs, csr_src, csr_ea,
                                                  We + j*256, atts + j*128, biases + j*128,
                                                  bufA /*residual*/, bufA, bufA_hi, bufA_lo);
  }

  // ---- pooling + fused dense trunk/heads ----
  pool_kernel<<<(NNODES + POOL_CHUNK - 1)/POOL_CHUNK, 128, 0, stream>>>(bufA, batch, sums, maxv, cnt);
  fused_dense<<<NBATCH, 128, 0, stream>>>(sums, maxv, cnt,
                                          D1_W, D1_b, D23_W, D23_b,
                                          H1_W, H1_b, H2_W, H2_b, H3_W, H3_b,
                                          (float*)d_out);
}

// Round 12
// 870.348 us; speedup vs baseline: 1.5524x; 1.0711x over previous
//
#include <hip/hip_runtime.h>
#include <hip/hip_bf16.h>
#include <cmath>

#define NNODES 50000
#define NEDGES 600000
#define NBATCH 50
#define SCAN_BLOCK 256
#define NCHUNK ((NNODES + SCAN_BLOCK - 1) / SCAN_BLOCK)   // 196
#define NSLABS (NNODES/16)                                // 3125 (exact)

typedef __attribute__((ext_vector_type(8))) short bf16x8;
typedef __attribute__((ext_vector_type(4))) float f32x4;

__device__ __forceinline__ float bf2f(ushort u){ return __uint_as_float(((unsigned)u) << 16); }

// ============================ CSR build ============================
__global__ void hist_kernel(const int* __restrict__ dst, int* __restrict__ deg){
  int e = blockIdx.x*blockDim.x + threadIdx.x;
  if(e < NEDGES) atomicAdd(&deg[dst[e]], 1);
}

__global__ void deg_partial(const int* __restrict__ deg, int* __restrict__ part){
  __shared__ int red[SCAN_BLOCK];
  int t = threadIdx.x, id = blockIdx.x*SCAN_BLOCK + t;
  red[t] = (id < NNODES) ? deg[id] : 0;
  __syncthreads();
  for(int o = SCAN_BLOCK/2; o > 0; o >>= 1){
    if(t < o) red[t] += red[t+o];
    __syncthreads();
  }
  if(t == 0) part[blockIdx.x] = red[0];
}

__global__ void part_scan(int* __restrict__ part){
  __shared__ int ps[256];
  int t = threadIdx.x;
  int v = (t < NCHUNK) ? part[t] : 0;
  ps[t] = v; __syncthreads();
  for(int o=1;o<256;o<<=1){
    int u = (t>=o) ? ps[t-o] : 0;
    __syncthreads();
    ps[t] += u;
    __syncthreads();
  }
  if(t < NCHUNK) part[t] = ps[t] - v;   // exclusive
}

__global__ void scan_final(const int* __restrict__ deg, const int* __restrict__ part,
                           int* __restrict__ off, int* __restrict__ cur){
  __shared__ int ps[SCAN_BLOCK];
  int t = threadIdx.x, id = blockIdx.x*SCAN_BLOCK + t;
  int v = (id < NNODES) ? deg[id] : 0;
  ps[t] = v; __syncthreads();
  for(int o=1;o<SCAN_BLOCK;o<<=1){
    int u = (t>=o) ? ps[t-o] : 0;
    __syncthreads();
    ps[t] += u;
    __syncthreads();
  }
  int excl = ps[t] - v + part[blockIdx.x];
  if(id < NNODES){ off[id] = excl; cur[id] = excl; }
  if(id == 0) off[NNODES] = NEDGES;
}

__global__ void scatter_kernel(const int* __restrict__ src, const int* __restrict__ dst,
                               const float* __restrict__ ea, int* __restrict__ cur,
                               int* __restrict__ csr_src, float2* __restrict__ csr_ea){
  int e = blockIdx.x*blockDim.x + threadIdx.x;
  if(e >= NEDGES) return;
  int d = dst[e];
  int p = atomicAdd(&cur[d], 1);
  csr_src[p] = src[e];
  csr_ea[p] = make_float2(ea[2*e], ea[2*e+1]);
}

// ============================ conv0 linear (K=4) ============================
__global__ void gemm_k4_dual(const float* __restrict__ x,
                             const float* __restrict__ Wa, const float* __restrict__ ba,
                             const float* __restrict__ Wb, const float* __restrict__ bb,
                             ushort* __restrict__ outa_bf, float* __restrict__ outb){
  int idx = blockIdx.x*blockDim.x + threadIdx.x;
  if(idx >= NNODES*128) return;
  int r = idx >> 7, c = idx & 127;
  float4 xv = *(const float4*)&x[r*4];
  float acca = ba[c] + xv.x*Wa[c] + xv.y*Wa[128+c] + xv.z*Wa[256+c] + xv.w*Wa[384+c];
  float accb = bb[c] + xv.x*Wb[c] + xv.y*Wb[128+c] + xv.z*Wb[256+c] + xv.w*Wb[384+c];
  __hip_bfloat16 h = __float2bfloat16(acca);
  outa_bf[idx] = *(ushort*)&h;
  outb[idx] = accb;
}

// ============================ W prep: bf16 hi/lo split + MFMA B-frag swizzle ============================
__global__ void wprep(const float* __restrict__ Wl, const float* __restrict__ Wr,
                      ushort* __restrict__ Bh, ushort* __restrict__ Blo){
  int idx = blockIdx.x*256 + threadIdx.x;   // 8 layers * 2 mats * 32 frags * 64 lanes = 32768
  int lane  = idx & 63;
  int f     = (idx >> 6) & 31;
  int mat   = (idx >> 11) & 1;
  int layer = idx >> 12;
  int ct = f >> 2, ks = f & 3;
  const float* W = (mat ? Wr : Wl) + (size_t)layer*16384;
  int krow = ks*32 + (lane>>4)*8;
  int col  = ct*16 + (lane&15);
  size_t base = ((size_t)(layer*2 + mat)*32 + f)*512 + lane*8;
  #pragma unroll
  for(int j=0;j<8;j++){
    float v = W[(krow+j)*128 + col];
    __hip_bfloat16 h = __float2bfloat16(v);
    __hip_bfloat16 l = __float2bfloat16(v - __bfloat162float(h));
    Bh[base+j]  = *(ushort*)&h;
    Blo[base+j] = *(ushort*)&l;
  }
}

// ============================ dual GEMM via MFMA (2-term split precision) ============================
// x@W ~= xh@Wh + xh@Wlo: W-side error ~2^-18, x-side 2^-9 (same as the bf16
// quantization the edge gather already applies). 32 MFMAs per slab.
__launch_bounds__(256)
__global__ void gemm_mfma(const ushort* __restrict__ xh,
                          const ushort* __restrict__ Bh, const ushort* __restrict__ Blo,
                          const float* __restrict__ ba, const float* __restrict__ bb,
                          ushort* __restrict__ outa_bf, float* __restrict__ outb){
  int tid = threadIdx.x;
  int lane = tid & 63;
  int gw = blockIdx.x*4 + (tid>>6);     // global wave id, 0..4095
  int cg = gw & 3;                      // col group: cols [cg*32, cg*32+32)
  int slab0 = gw >> 2;                  // 0..1023
  int m = lane & 15, quad = lane >> 4;

  bf16x8 Bf[2][2][2][4];                // [mat][term][c][ks]
  #pragma unroll
  for(int mat=0;mat<2;mat++)
    #pragma unroll
    for(int c=0;c<2;c++)
      #pragma unroll
      for(int ks=0;ks<4;ks++){
        size_t o = ((size_t)mat*32 + (size_t)(cg*2+c)*4 + ks)*512 + lane*8;
        Bf[mat][0][c][ks] = *(const bf16x8*)&Bh[o];
        Bf[mat][1][c][ks] = *(const bf16x8*)&Blo[o];
      }
  float bav[2] = { ba[cg*32 + m], ba[cg*32 + 16 + m] };
  float bbv[2] = { bb[cg*32 + m], bb[cg*32 + 16 + m] };

  for(int slab = slab0; slab < NSLABS; slab += 1024){
    int row0 = slab*16;
    const ushort* pa = xh + (size_t)(row0+m)*128 + quad*8;
    f32x4 acc[2][2];
    #pragma unroll
    for(int mat=0;mat<2;mat++)
      #pragma unroll
      for(int c=0;c<2;c++) acc[mat][c] = (f32x4){0.f,0.f,0.f,0.f};
    #pragma unroll
    for(int ks=0;ks<4;ks++){
      bf16x8 Ah = *(const bf16x8*)(pa + ks*32);
      #pragma unroll
      for(int mat=0;mat<2;mat++)
        #pragma unroll
        for(int c=0;c<2;c++){
          acc[mat][c] = __builtin_amdgcn_mfma_f32_16x16x32_bf16(Ah, Bf[mat][0][c][ks], acc[mat][c], 0,0,0);
          acc[mat][c] = __builtin_amdgcn_mfma_f32_16x16x32_bf16(Ah, Bf[mat][1][c][ks], acc[mat][c], 0,0,0);
        }
    }
    #pragma unroll
    for(int c=0;c<2;c++){
      int col = cg*32 + c*16 + m;
      #pragma unroll
      for(int r=0;r<4;r++){
        int row = row0 + quad*4 + r;
        float va = acc[0][c][r] + bav[c];
        __hip_bfloat16 h = __float2bfloat16(va);
        outa_bf[(size_t)row*128 + col] = *(ushort*)&h;
        outb[(size_t)row*128 + col] = acc[1][c][r] + bbv[c];
      }
    }
  }
}

// ============================ fused GATv2 edge phase ============================
// Fixed-reference softmax: subtract the self-loop logit m0 (shift-invariant,
// logits O(0.3) so no overflow) -> no running max / rescale, no loop-carried dep.
// Gathers bf16 xl rows; ILP=4; indices scalar via readfirstlane.
__launch_bounds__(256)
__global__ void edge_kernel(const ushort* __restrict__ xlb, const float* __restrict__ xr,
                            const int* __restrict__ off, const int* __restrict__ csr_src,
                            const float2* __restrict__ csr_ea,
                            const float* __restrict__ We, const float* __restrict__ att,
                            const float* __restrict__ bias, const float* __restrict__ res,
                            float* __restrict__ out, ushort* __restrict__ out_hi){
  int wid  = (blockIdx.x*blockDim.x + threadIdx.x) >> 6;
  int lane = threadIdx.x & 63;
  if(wid >= NNODES) return;
  int node = __builtin_amdgcn_readfirstlane(wid);
  int c0 = lane*2;
  float2 xr2 = *(const float2*)&xr[node*128 + c0];
  ushort2 su = *(const ushort2*)&xlb[node*128 + c0];
  float2 xls = make_float2(bf2f(su.x), bf2f(su.y));
  float2 av  = *(const float2*)&att[c0];
  float2 w0  = *(const float2*)&We[c0];
  float2 w1  = *(const float2*)&We[128 + c0];

  // self-loop logit (src=node, ea=0) -> reference m0
  float zx = xls.x + xr2.x; zx = zx > 0.f ? zx : 0.2f*zx;
  float zy = xls.y + xr2.y; zy = zy > 0.f ? zy : 0.2f*zy;
  float m0 = zx*av.x + zy*av.y;
  #pragma unroll
  for(int o=1;o<16;o<<=1) m0 += __shfl_xor(m0, o, 64);
  float den = 1.f;                      // exp(m0 - m0)
  float accx = xls.x, accy = xls.y;

  int e0 = off[node], e1 = off[node+1];
  for(int e=e0; e<e1; e+=4){
    int cnt = e1 - e;
    int   s[4];
    float2 ea[4];
    #pragma unroll
    for(int j=0;j<4;j++){
      if(j < cnt){
        s[j]  = __builtin_amdgcn_readfirstlane(csr_src[e+j]);
        ea[j] = csr_ea[e+j];
      } else {
        s[j] = node; ea[j] = make_float2(0.f,0.f);
      }
    }
    float2 xv[4];
    #pragma unroll
    for(int j=0;j<4;j++){
      ushort2 u = *(const ushort2*)&xlb[(size_t)s[j]*128 + c0];
      xv[j] = make_float2(bf2f(u.x), bf2f(u.y));
    }
    float p[4];
    #pragma unroll
    for(int j=0;j<4;j++){
      float z0 = xv[j].x + xr2.x + ea[j].x*w0.x + ea[j].y*w1.x; z0 = z0 > 0.f ? z0 : 0.2f*z0;
      float z1 = xv[j].y + xr2.y + ea[j].x*w0.y + ea[j].y*w1.y; z1 = z1 > 0.f ? z1 : 0.2f*z1;
      p[j] = z0*av.x + z1*av.y;
    }
    #pragma unroll
    for(int o=1;o<16;o<<=1){
      #pragma unroll
      for(int j=0;j<4;j++) p[j] += __shfl_xor(p[j], o, 64);
    }
    #pragma unroll
    for(int j=0;j<4;j++) if(j >= cnt) p[j] = -1e30f;   // exp -> 0
    float pe[4];
    #pragma unroll
    for(int j=0;j<4;j++) pe[j] = __expf(p[j] - m0);
    den  += pe[0]+pe[1]+pe[2]+pe[3];
    accx += pe[0]*xv[0].x + pe[1]*xv[1].x + pe[2]*xv[2].x + pe[3]*xv[3].x;
    accy += pe[0]*xv[0].y + pe[1]*xv[1].y + pe[2]*xv[2].y + pe[3]*xv[3].y;
  }
  float inv = 1.f/(den + 1e-16f);
  float ox = accx*inv + bias[c0];
  float oy = accy*inv + bias[c0+1];
  ox = ox > 0.f ? ox : 0.f;
  oy = oy > 0.f ? oy : 0.f;
  if(res){ ox += res[node*128 + c0]; oy += res[node*128 + c0 + 1]; }
  *(float2*)&out[node*128 + c0] = make_float2(ox, oy);
  __hip_bfloat16 hx = __float2bfloat16(ox);
  __hip_bfloat16 hy = __float2bfloat16(oy);
  *(ushort2*)&out_hi[node*128 + c0] = make_ushort2(*(ushort*)&hx, *(ushort*)&hy);
}

// ============================ pooling ============================
#define POOL_CHUNK 128
__launch_bounds__(128)
__global__ void pool_kernel(const float* __restrict__ x, const int* __restrict__ batch,
                            float* __restrict__ sums, float* __restrict__ maxv,
                            float* __restrict__ cnt){
  int c = threadIdx.x;
  int n0 = blockIdx.x * POOL_CHUNK;
  if(n0 >= NNODES) return;
  int n1 = n0 + POOL_CHUNK; if(n1 > NNODES) n1 = NNODES;
  int curb = batch[n0];
  float s = 0.f, mx = 0.f;
  float segc = 0.f;
  for(int nd = n0; nd < n1; nd++){
    int b = batch[nd];
    if(b != curb){
      atomicAdd(&sums[curb*128 + c], s);
      atomicMax((int*)&maxv[curb*128 + c], __float_as_int(mx));
      if(c == 0) atomicAdd(&cnt[curb], segc);
      curb = b; s = 0.f; mx = 0.f; segc = 0.f;
    }
    float v = x[nd*128 + c];
    s += v; mx = fmaxf(mx, v); segc += 1.f;
  }
  atomicAdd(&sums[curb*128 + c], s);
  atomicMax((int*)&maxv[curb*128 + c], __float_as_int(mx));
  if(c == 0) atomicAdd(&cnt[curb], segc);
}

// ============================ fused dense trunk + heads ============================
__launch_bounds__(128)
__global__ void fused_dense(const float* __restrict__ sums, const float* __restrict__ maxv,
                            const float* __restrict__ cnt,
                            const float* __restrict__ D1_W, const float* __restrict__ D1_b,
                            const float* __restrict__ D23_W, const float* __restrict__ D23_b,
                            const float* __restrict__ H1_W, const float* __restrict__ H1_b,
                            const float* __restrict__ H2_W, const float* __restrict__ H2_b,
                            const float* __restrict__ H3_W, const float* __restrict__ H3_b,
                            float* __restrict__ out){
  __shared__ float X[256];
  __shared__ float y[128];
  __shared__ float z[128];
  int b = blockIdx.x, t = threadIdx.x;
  float ct = cnt[b]; ct = ct > 1.f ? ct : 1.f;
  X[t]       = sums[b*128 + t] / ct;
  X[128 + t] = maxv[b*128 + t];
  __syncthreads();
  float acc = D1_b[t];
  #pragma unroll 16
  for(int k=0;k<256;k++) acc += X[k]*D1_W[k*128+t];
  y[t] = fmaxf(acc, 0.f);
  __syncthreads();
  acc = D23_b[t];
  #pragma unroll 16
  for(int k=0;k<128;k++) acc += y[k]*D23_W[k*128+t];
  z[t] = fmaxf(acc, 0.f);
  __syncthreads();
  acc = D23_b[128+t];
  #pragma unroll 16
  for(int k=0;k<128;k++) acc += z[k]*D23_W[16384 + k*128+t];
  y[t] = fmaxf(acc, 0.f);
  __syncthreads();
  for(int h=0;h<3;h++){
    acc = H1_b[h*128+t];
    #pragma unroll 16
    for(int k=0;k<128;k++) acc += y[k]*H1_W[h*16384 + k*128+t];
    z[t] = fmaxf(acc, 0.f);
    __syncthreads();
    float v = 0.f;
    if(t < 64){
      float a2 = H2_b[h*64+t];
      #pragma unroll 16
      for(int k=0;k<128;k++) a2 += z[k]*H2_W[h*8192 + k*64+t];
      a2 = fmaxf(a2, 0.f);
      v = a2 * H3_W[h*64 + t];
    }
    #pragma unroll
    for(int o=1;o<64;o<<=1) v += __shfl_xor(v, o, 64);
    if(t == 0){
      float r = v + H3_b[h];
      if(h == 0) r = tanhf(r);
      out[b*3 + h] = r;
    }
    __syncthreads();
  }
}

// ============================ launch ============================
extern "C" void kernel_launch(void* const* d_in, const int* in_sizes, int n_in,
                              void* d_out, int out_size, void* d_ws, size_t ws_size,
                              hipStream_t stream) {
  const float* nodes  = (const float*)d_in[0];
  const int*   eidx   = (const int*)  d_in[1];
  const float* eattr  = (const float*)d_in[2];
  const int*   batch  = (const int*)  d_in[3];
  const float* W0l    = (const float*)d_in[4];
  const float* b0l    = (const float*)d_in[5];
  const float* W0r    = (const float*)d_in[6];
  const float* b0r    = (const float*)d_in[7];
  const float* W0e    = (const float*)d_in[8];
  const float* att0   = (const float*)d_in[9];
  const float* bias0  = (const float*)d_in[10];
  const float* Wl     = (const float*)d_in[11];
  const float* bl     = (const float*)d_in[12];
  const float* Wr     = (const float*)d_in[13];
  const float* br     = (const float*)d_in[14];
  const float* We     = (const float*)d_in[15];
  const float* atts   = (const float*)d_in[16];
  const float* biases = (const float*)d_in[17];
  const float* D1_W   = (const float*)d_in[18];
  const float* D1_b   = (const float*)d_in[19];
  const float* D23_W  = (const float*)d_in[20];
  const float* D23_b  = (const float*)d_in[21];
  const float* H1_W   = (const float*)d_in[22];
  const float* H1_b   = (const float*)d_in[23];
  const float* H2_W   = (const float*)d_in[24];
  const float* H2_b   = (const float*)d_in[25];
  const float* H3_W   = (const float*)d_in[26];
  const float* H3_b   = (const float*)d_in[27];

  // ---- workspace layout ----
  char* ws = (char*)d_ws;
  size_t o = 0;
  auto alloc = [&](size_t bytes)->char*{ char* p = ws + o; o = (o + bytes + 255) & ~(size_t)255; return p; };
  int*    deg     = (int*)   alloc(NNODES*4);
  int*    offs    = (int*)   alloc((NNODES+1)*4);
  int*    cur     = (int*)   alloc(NNODES*4);
  int*    part    = (int*)   alloc(NCHUNK*4);
  int*    csr_src = (int*)   alloc(NEDGES*4);
  float2* csr_ea  = (float2*)alloc(NEDGES*8);
  ushort* xlb     = (ushort*)alloc((size_t)NNODES*128*2);   // bf16 xl (gather target)
  float*  xr      = (float*) alloc((size_t)NNODES*128*4);
  float*  bufA    = (float*) alloc((size_t)NNODES*128*4);
  float*  bufB    = (float*) alloc((size_t)NNODES*128*4);
  ushort* bufA_hi = (ushort*)alloc((size_t)NNODES*128*2);
  ushort* bufB_hi = (ushort*)alloc((size_t)NNODES*128*2);
  ushort* Bh      = (ushort*)alloc((size_t)8*2*32*512*2);   // swizzled W hi
  ushort* Blo     = (ushort*)alloc((size_t)8*2*32*512*2);   // swizzled W lo
  float*  pool    = (float*) alloc((NBATCH*128*2 + NBATCH)*4);
  float*  sums    = pool;
  float*  maxv    = pool + NBATCH*128;
  float*  cnt     = pool + NBATCH*256;
  (void)ws_size; (void)in_sizes; (void)n_in; (void)out_size;

  const int* src = eidx;
  const int* dst = eidx + NEDGES;

  // ---- CSR build + W prep ----
  hipMemsetAsync(deg, 0, NNODES*4, stream);
  hipMemsetAsync(pool, 0, (NBATCH*128*2 + NBATCH)*4, stream);
  hist_kernel<<<(NEDGES+255)/256, 256, 0, stream>>>(dst, deg);
  deg_partial<<<NCHUNK, SCAN_BLOCK, 0, stream>>>(deg, part);
  part_scan<<<1, 256, 0, stream>>>(part);
  scan_final<<<NCHUNK, SCAN_BLOCK, 0, stream>>>(deg, part, offs, cur);
  scatter_kernel<<<(NEDGES+255)/256, 256, 0, stream>>>(src, dst, eattr, cur, csr_src, csr_ea);
  wprep<<<128, 256, 0, stream>>>(Wl, Wr, Bh, Blo);

  // ---- conv0 ----
  gemm_k4_dual<<<(NNODES*128+255)/256, 256, 0, stream>>>(nodes, W0l, b0l, W0r, b0r, xlb, xr);
  edge_kernel<<<(NNODES+3)/4, 256, 0, stream>>>(xlb, xr, offs, csr_src, csr_ea,
                                                W0e, att0, bias0, nullptr, bufA, bufA_hi);

  // ---- 4 skip blocks x 2 convs ----
  const size_t wstride = (size_t)2*32*512;   // per-layer stride in swizzled W
  for(int blk=0; blk<4; blk++){
    int j = 2*blk;
    gemm_mfma<<<1024, 256, 0, stream>>>(bufA_hi, Bh + (size_t)j*wstride, Blo + (size_t)j*wstride,
                                        bl + j*128, br + j*128, xlb, xr);
    edge_kernel<<<(NNODES+3)/4, 256, 0, stream>>>(xlb, xr, offs, csr_src, csr_ea,
                                                  We + j*256, atts + j*128, biases + j*128,
                                                  nullptr, bufB, bufB_hi);
    j = 2*blk + 1;
    gemm_mfma<<<1024, 256, 0, stream>>>(bufB_hi, Bh + (size_t)j*wstride, Blo + (size_t)j*wstride,
                                        bl + j*128, br + j*128, xlb, xr);
    edge_kernel<<<(NNODES+3)/4, 256, 0, stream>>>(xlb, xr, offs, csr_src, csr_ea,
                                                  We + j*256, atts + j*128, biases + j*128,
                                                  bufA /*residual*/, bufA, bufA_hi);
  }

  // ---- pooling + fused dense trunk/heads ----
  pool_kernel<<<(NNODES + POOL_CHUNK - 1)/POOL_CHUNK, 128, 0, stream>>>(bufA, batch, sums, maxv, cnt);
  fused_dense<<<NBATCH, 128, 0, stream>>>(sums, maxv, cnt,
                                          D1_W, D1_b, D23_W, D23_b,
                                          H1_W, H1_b, H2_W, H2_b, H3_W, H3_b,
                                          (float*)d_out);
}